// Round 6
// baseline (3260.186 us; speedup 1.0000x reference)
//
#include <hip/hip_runtime.h>
#include <stdint.h>

#define SS 512
#define BB 64
#define HH 256
#define TT 32

typedef __attribute__((ext_vector_type(8))) short bf16x8;
typedef __attribute__((ext_vector_type(4))) short short4v;
typedef __attribute__((ext_vector_type(4))) float f32x4;

__device__ __forceinline__ unsigned short f2bf(float f){
  unsigned u = __float_as_uint(f);
  unsigned r = (u + 0x7FFFu + ((u >> 16) & 1u)) >> 16;
  return (unsigned short)r;
}
__device__ __forceinline__ float bf2f(unsigned short s){
  return __uint_as_float(((unsigned)s) << 16);
}
__device__ __forceinline__ float sigm(float x){ return 1.0f/(1.0f+__expf(-x)); }
__device__ __forceinline__ float ftanh(float x){
  float e = __expf(2.f*x);
  return 1.f - 2.f/(e + 1.f);
}
__device__ __forceinline__ unsigned cvt4fp8(float a0, float a1, float a2, float a3){
  int d = __builtin_amdgcn_cvt_pk_fp8_f32(a0, a1, 0, false);
  d = __builtin_amdgcn_cvt_pk_fp8_f32(a2, a3, d, true);
  return (unsigned)d;
}

// swizzled-LDS fragment read (used by k_xgemm only)
__device__ __forceinline__ bf16x8 afrag(const unsigned short* A, int mt, int ktp, int nl, int kq){
  int m = mt*16 + nl;
  int sw = (m & 7) << 3;
  int kk = ktp*32 + kq*4;
  short4v lo = *(const short4v*)(A + (m << 8) + (kk ^ sw));
  short4v hi = *(const short4v*)(A + (m << 8) + ((kk + 16) ^ sw));
  bf16x8 r = {lo[0],lo[1],lo[2],lo[3],hi[0],hi[1],hi[2],hi[3]};
  return r;
}

// ---------------- fused gather + x@Wih^T GEMM -> gx bf16 [dir][t][col(1024)][b(64)] ----------------
__global__ __launch_bounds__(256,1) void k_xgemm(
    const int* __restrict__ seq, const float* __restrict__ emb,
    const float* __restrict__ Wih_f, const float* __restrict__ Wih_b,
    unsigned short* __restrict__ gx)
{
  __shared__ __align__(16) unsigned short A_l[128*256];  // 64 KiB
  __shared__ __align__(16) unsigned short B_l[64*256];   // 32 KiB

  const int tid = threadIdx.x;
  const int lane = tid & 63, w = tid >> 6;
  const int nl = lane & 15, kq = lane >> 4;
  const int pbase = blockIdx.x * 128;
  const int dir = blockIdx.y;
  const float* Wih = dir ? Wih_b : Wih_f;
  unsigned short* gxd = gx + (size_t)dir*SS*1024*64;

#pragma unroll
  for (int i = 0; i < 16; ++i){
    int c = tid + i*256;
    int m = c >> 5, k8 = c & 31;
    int p = pbase + m, t = p >> 6, b = p & 63;
    int er = seq[b*SS + t];
    const float* s = emb + (size_t)er*HH + k8*8;
    float4 x0 = *(const float4*)s, x1 = *(const float4*)(s+4);
    union { unsigned short u[8]; uint4 v; } o;
    o.u[0]=f2bf(x0.x); o.u[1]=f2bf(x0.y); o.u[2]=f2bf(x0.z); o.u[3]=f2bf(x0.w);
    o.u[4]=f2bf(x1.x); o.u[5]=f2bf(x1.y); o.u[6]=f2bf(x1.z); o.u[7]=f2bf(x1.w);
    *(uint4*)&A_l[(m << 8) + ((k8*8) ^ ((m & 7) << 3))] = o.v;
  }

  for (int nb = 0; nb < 16; ++nb){
    __syncthreads();
#pragma unroll
    for (int i = 0; i < 8; ++i){
      int c = tid + i*256;
      int m = c >> 5, k8 = c & 31;
      const float* s = Wih + (size_t)(nb*64 + m)*HH + k8*8;
      float4 x0 = *(const float4*)s, x1 = *(const float4*)(s+4);
      union { unsigned short u[8]; uint4 v; } o;
      o.u[0]=f2bf(x0.x); o.u[1]=f2bf(x0.y); o.u[2]=f2bf(x0.z); o.u[3]=f2bf(x0.w);
      o.u[4]=f2bf(x1.x); o.u[5]=f2bf(x1.y); o.u[6]=f2bf(x1.z); o.u[7]=f2bf(x1.w);
      *(uint4*)&B_l[(m << 8) + ((k8*8) ^ ((m & 7) << 3))] = o.v;
    }
    __syncthreads();

    f32x4 acc[2][4];
#pragma unroll
    for (int mt = 0; mt < 2; ++mt)
#pragma unroll
      for (int nt = 0; nt < 4; ++nt) acc[mt][nt] = (f32x4){0.f,0.f,0.f,0.f};

#pragma unroll
    for (int kt = 0; kt < 8; ++kt){
      bf16x8 a0 = afrag(A_l, w*2+0, kt, nl, kq);
      bf16x8 a1 = afrag(A_l, w*2+1, kt, nl, kq);
#pragma unroll
      for (int nt = 0; nt < 4; ++nt){
        bf16x8 bv = afrag(B_l, nt, kt, nl, kq);
        acc[0][nt] = __builtin_amdgcn_mfma_f32_16x16x32_bf16(a0, bv, acc[0][nt], 0,0,0);
        acc[1][nt] = __builtin_amdgcn_mfma_f32_16x16x32_bf16(a1, bv, acc[1][nt], 0,0,0);
      }
    }

#pragma unroll
    for (int mt = 0; mt < 2; ++mt)
#pragma unroll
      for (int nt = 0; nt < 4; ++nt){
        int p0 = pbase + w*32 + mt*16 + kq*4;
        int t = p0 >> 6, b0 = p0 & 63;
        int col = nb*64 + nt*16 + nl;
        union { unsigned short u[4]; uint2 v; } o;
        o.u[0]=f2bf(acc[mt][nt][0]); o.u[1]=f2bf(acc[mt][nt][1]);
        o.u[2]=f2bf(acc[mt][nt][2]); o.u[3]=f2bf(acc[mt][nt][3]);
        *(uint2*)(gxd + ((size_t)t*1024 + col)*64 + b0) = o.v;
      }
  }
}

// ---------------- batch-partitioned bidirectional LSTM: ZERO cross-CU communication ----------------
// 8 blocks x 512 threads: blocks 0..3 fwd (batch rows blk*16..+15), 4..7 bwd.
// Whole Whh lives in VGPRs as fp8 e4m3 (x64 scale); h recurrence stays inside the CU:
// fp8 frag-packed LDS tile (double-buffered), one __syncthreads per step.
// Wave w owns h-col tiles {2w, 2w+1} x all 4 gates (8 n-tiles, lane-local gate combine).
#define WSC 64.0f
#define HSC 16.0f
#define ISC (1.0f/(WSC*HSC))

__global__ __launch_bounds__(512,2) void k_lstm(
    const unsigned short* __restrict__ gx,
    const float* __restrict__ Whh_f, const float* __restrict__ bih_f, const float* __restrict__ bhh_f,
    const float* __restrict__ Whh_b, const float* __restrict__ bih_b, const float* __restrict__ bhh_b,
    unsigned short* __restrict__ hf, unsigned short* __restrict__ hb)
{
  __shared__ __align__(16) unsigned char h8[2][16][272];   // fp8 h, frag-packed, padded rows
  __shared__ float stg[8][2][16][17];                      // per-wave transpose staging

  const int tid  = threadIdx.x;
  const int lane = tid & 63;
  const int w    = tid >> 6;           // 0..7
  const int nl   = lane & 15;
  const int kq   = lane >> 4;
  const int dir  = blockIdx.x >> 2;
  const int b0   = (blockIdx.x & 3) * 16;   // batch base

  const float* Whh = dir ? Whh_b : Whh_f;
  const float* bih = dir ? bih_b : bih_f;
  const float* bhh = dir ? bhh_b : bhh_f;
  unsigned short* hbuf = dir ? hb : hf;
  const unsigned short* gxd = gx + (size_t)dir*SS*1024*64;

  // Whh -> fp8 B-fragments in VGPRs: wB[gate][q][kt], 64 longs = 128 VGPR/lane
  long wB[4][2][8];
#pragma unroll
  for (int g = 0; g < 4; ++g)
#pragma unroll
    for (int q = 0; q < 2; ++q)
#pragma unroll
      for (int kt = 0; kt < 8; ++kt){
        int ncol = g*256 + (2*w + q)*16 + nl;
        const float* p = Whh + (size_t)ncol*HH + kt*32 + kq*4;
        float4 lo = *(const float4*)p;
        float4 hi = *(const float4*)(p + 16);
        union { unsigned d[2]; long l; } u;
        u.d[0] = cvt4fp8(lo.x*WSC, lo.y*WSC, lo.z*WSC, lo.w*WSC);
        u.d[1] = cvt4fp8(hi.x*WSC, hi.y*WSC, hi.z*WSC, hi.w*WSC);
        wB[g][q][kt] = u.l;
      }

  float bias[4][2];
#pragma unroll
  for (int g = 0; g < 4; ++g)
#pragma unroll
    for (int q = 0; q < 2; ++q){
      int col = g*256 + (2*w + q)*16 + nl;
      bias[g][q] = bih[col] + bhh[col];
    }

  // zero h tile (h_0 = 0)
  for (int i = tid; i < 2176; i += 512) ((unsigned*)h8)[i] = 0;
  __syncthreads();

  float c[2][4] = {{0.f,0.f,0.f,0.f},{0.f,0.f,0.f,0.f}};

  for (int s = 0; s < SS; ++s){
    const int t = dir ? (SS-1-s) : s;

    // gx prefetch (recurrence-independent; hides under MFMA)
    union { uint2 v; unsigned short u[4]; } gxu[4][2];
#pragma unroll
    for (int g = 0; g < 4; ++g)
#pragma unroll
      for (int q = 0; q < 2; ++q){
        int col = g*256 + (2*w + q)*16 + nl;
        gxu[g][q].v = *(const uint2*)(gxd + ((size_t)t*1024 + col)*64 + b0 + kq*4);
      }

    // A-fragments: one ds_read_b64 per kt from frag-packed fp8 tile
    const unsigned char* tp = &h8[s & 1][0][0];
    long af[8];
#pragma unroll
    for (int kt = 0; kt < 8; ++kt)
      af[kt] = *(const long*)(tp + nl*272 + kt*32 + kq*8);

    f32x4 acc[4][2];
#pragma unroll
    for (int g = 0; g < 4; ++g)
#pragma unroll
      for (int q = 0; q < 2; ++q) acc[g][q] = (f32x4){0.f,0.f,0.f,0.f};

#pragma unroll
    for (int kt = 0; kt < 8; ++kt)
#pragma unroll
      for (int g = 0; g < 4; ++g)
#pragma unroll
        for (int q = 0; q < 2; ++q)
          acc[g][q] = __builtin_amdgcn_mfma_f32_16x16x32_fp8_fp8(af[kt], wB[g][q][kt], acc[g][q], 0,0,0);

    // gate combine (lane-local: D row kq*4+r = batch, col nl) -> stage f32 h for transpose
#pragma unroll
    for (int q = 0; q < 2; ++q)
#pragma unroll
      for (int r = 0; r < 4; ++r){
        float iv = acc[0][q][r]*ISC + bf2f(gxu[0][q].u[r]) + bias[0][q];
        float fv = acc[1][q][r]*ISC + bf2f(gxu[1][q].u[r]) + bias[1][q];
        float gv = acc[2][q][r]*ISC + bf2f(gxu[2][q].u[r]) + bias[2][q];
        float ov = acc[3][q][r]*ISC + bf2f(gxu[3][q].u[r]) + bias[3][q];
        float cc = sigm(fv)*c[q][r] + sigm(iv)*ftanh(gv);
        c[q][r] = cc;
        stg[w][q][kq*4 + r][nl] = sigm(ov)*ftanh(cc);
      }

    // per-wave 16x16 transpose readback; dual store: global bf16 + LDS fp8 (next tile)
    const int wslot = dir ? t : (s + 1);
#pragma unroll
    for (int q = 0; q < 2; ++q){
      float v0 = stg[w][q][nl][kq*4 + 0];
      float v1 = stg[w][q][nl][kq*4 + 1];
      float v2 = stg[w][q][nl][kq*4 + 2];
      float v3 = stg[w][q][nl][kq*4 + 3];
      uint2 hv;
      hv.x = ((unsigned)f2bf(v1) << 16) | f2bf(v0);
      hv.y = ((unsigned)f2bf(v3) << 16) | f2bf(v2);
      *(uint2*)(hbuf + (size_t)wslot*BB*HH + (size_t)(b0 + nl)*HH + (2*w + q)*16 + kq*4) = hv;
      unsigned f8 = cvt4fp8(v0*HSC, v1*HSC, v2*HSC, v3*HSC);
      int tc = 2*w + q;
      *(unsigned*)&h8[(s + 1) & 1][nl][(tc >> 1)*32 + kq*8 + (tc & 1)*4] = f8;
    }

    __syncthreads();
  }
}

// ---------------- FC via MFMA: logits[p][tag] = [hf(t+1);hb(t)] . fcW[tag] + fcb ----------------
__global__ __launch_bounds__(256,1) void k_fc(
    const unsigned short* __restrict__ hf, const unsigned short* __restrict__ hb,
    const float* __restrict__ fcW, const float* __restrict__ fcb,
    float* __restrict__ logits)
{
  __shared__ unsigned short Bs[32][520];
  __shared__ float fcb_s[32];
  const int tid = threadIdx.x;
  for (int i = tid; i < 32*512; i += 256){
    int tg = i >> 9, k = i & 511;
    Bs[tg][k] = f2bf(fcW[tg*512 + k]);
  }
  if (tid < 32) fcb_s[tid] = fcb[tid];
  __syncthreads();

  const int lane = tid & 63, w = tid >> 6;
  const int nl = lane & 15, kq = lane >> 4;
  const int pbase = blockIdx.x * 128;

  f32x4 acc[2][2];
#pragma unroll
  for (int mt = 0; mt < 2; ++mt)
#pragma unroll
    for (int nt = 0; nt < 2; ++nt) acc[mt][nt] = (f32x4){0.f,0.f,0.f,0.f};

#pragma unroll
  for (int kt = 0; kt < 16; ++kt){
    int k0 = kt*32 + kq*4;
    bf16x8 a[2];
#pragma unroll
    for (int mt = 0; mt < 2; ++mt){
      int p = pbase + w*32 + mt*16 + nl;
      int t = p >> 6, b = p & 63;
      const unsigned short* hrp = (kt < 8)
        ? hf + (size_t)((t+1)*BB + b)*HH + k0
        : hb + (size_t)(t*BB + b)*HH + (k0 - 256);
      short4v lo = *(const short4v*)hrp;
      short4v hi = *(const short4v*)(hrp + 16);
      bf16x8 f = {lo[0],lo[1],lo[2],lo[3],hi[0],hi[1],hi[2],hi[3]};
      a[mt] = f;
    }
#pragma unroll
    for (int nt = 0; nt < 2; ++nt){
      const unsigned short* br = &Bs[nt*16 + nl][k0];
      short4v lo = *(const short4v*)br;
      short4v hi = *(const short4v*)(br + 16);
      bf16x8 bv = {lo[0],lo[1],lo[2],lo[3],hi[0],hi[1],hi[2],hi[3]};
      acc[0][nt] = __builtin_amdgcn_mfma_f32_16x16x32_bf16(a[0], bv, acc[0][nt], 0,0,0);
      acc[1][nt] = __builtin_amdgcn_mfma_f32_16x16x32_bf16(a[1], bv, acc[1][nt], 0,0,0);
    }
  }
#pragma unroll
  for (int mt = 0; mt < 2; ++mt)
#pragma unroll
    for (int nt = 0; nt < 2; ++nt)
#pragma unroll
      for (int r = 0; r < 4; ++r){
        int p = pbase + w*32 + mt*16 + kq*4 + r;
        int tg = nt*16 + nl;
        logits[(size_t)p*TT + tg] = acc[mt][nt][r] + fcb_s[tg];
      }
}

// ---------------- merged CRF: blocks 0-15 den, 16-31 vit, 32-47 num ----------------
__global__ void k_crf(const float* __restrict__ logits, const int* __restrict__ mask,
                      const int* __restrict__ labels,
                      const float* __restrict__ start, const float* __restrict__ endt,
                      const float* __restrict__ trans,
                      float* __restrict__ den, float* __restrict__ num,
                      unsigned char* __restrict__ vhist, float* __restrict__ preds)
{
  __shared__ float tr[1024];
  const int tid = threadIdx.x;
  const int role = blockIdx.x >> 4;
  const int bq   = blockIdx.x & 15;
  if (role != 2){
    for (int i = tid; i < 1024; i += 256) tr[i] = trans[i];
    __syncthreads();
  }
  const int lane = tid & 63, w = tid >> 6;
  const int b = bq*4 + w;
  const int grp = lane >> 5, tp = lane & 31;

  if (role == 0){ // denominator
    float score = start[tp] + logits[(size_t)b*TT + tp];
    for (int s = 1; s < SS; ++s){
      float m = -1e30f;
#pragma unroll
      for (int jj = 0; jj < 16; ++jj){
        int j = grp*16 + jj;
        float v = __shfl(score, j) + tr[j*32 + tp];
        m = fmaxf(m, v);
      }
      m = fmaxf(m, __shfl_xor(m, 32));
      float ssum = 0.f;
#pragma unroll
      for (int jj = 0; jj < 16; ++jj){
        int j = grp*16 + jj;
        float v = __shfl(score, j) + tr[j*32 + tp];
        ssum += __expf(v - m);
      }
      ssum += __shfl_xor(ssum, 32);
      float ns = m + __logf(ssum) + logits[(size_t)(s*BB + b)*TT + tp];
      score = mask[b*SS + s] ? ns : score;
    }
    float v = score + endt[tp];
    float mm = v;
    for (int d = 1; d < 32; d <<= 1) mm = fmaxf(mm, __shfl_xor(mm, d));
    float se = __expf(v - mm);
    for (int d = 1; d < 32; d <<= 1) se += __shfl_xor(se, d);
    if (lane == 0) den[b] = mm + __logf(se);
  } else if (role == 1){ // viterbi
    float score = start[tp] + logits[(size_t)b*TT + tp];
    for (int s = 1; s < SS; ++s){
      float m = -1e30f; int am = 0;
#pragma unroll
      for (int jj = 0; jj < 16; ++jj){
        int j = grp*16 + jj;
        float v = __shfl(score, j) + tr[j*32 + tp];
        if (v > m){ m = v; am = j; }
      }
      float om = __shfl_xor(m, 32); int oam = __shfl_xor(am, 32);
      if (om > m || (om == m && oam < am)){ m = om; am = oam; }
      int mk = mask[b*SS + s];
      float ns = m + logits[(size_t)(s*BB + b)*TT + tp];
      int idx = mk ? am : tp;
      if (grp == 0) vhist[(size_t)(s*BB + b)*32 + tp] = (unsigned char)idx;
      score = mk ? ns : score;
    }
    float v = score + endt[tp]; int a = tp;
    for (int d = 1; d < 32; d <<= 1){
      float ov = __shfl_xor(v, d); int oa = __shfl_xor(a, d);
      if (ov > v || (ov == v && oa < a)){ v = ov; a = oa; }
    }
    int tag = __shfl(a, 0);
    if (lane == 0) preds[(size_t)b*SS + SS - 1] = (float)tag;
    for (int s = SS - 1; s >= 1; --s){
      int rv = vhist[(size_t)(s*BB + b)*32 + tp];
      int pv = __shfl(rv, tag);
      if (lane == 0) preds[(size_t)b*SS + s - 1] = (float)pv;
      tag = pv;
    }
  } else { // numerator
    float acc = 0.f; int mcnt = 0;
    for (int s = lane; s < SS; s += 64){
      int mk = mask[b*SS + s];
      mcnt += mk;
      if (s >= 1){
        int tg = labels[b*SS + s], tpp = labels[b*SS + s - 1];
        float v = trans[tpp*32 + tg] + logits[(size_t)(s*BB + b)*TT + tg];
        acc += mk ? v : 0.f;
      }
    }
    for (int d = 1; d < 64; d <<= 1){ acc += __shfl_xor(acc, d); mcnt += __shfl_xor(mcnt, d); }
    if (lane == 0){
      int t0 = labels[b*SS];
      int tl = labels[b*SS + (mcnt - 1)];
      num[b] = start[t0] + logits[(size_t)b*TT + t0] + acc + endt[tl];
    }
  }
}

// ---------------- loss ----------------
__global__ void k_loss(const float* __restrict__ num, const float* __restrict__ den,
                       float* __restrict__ out)
{
  int l = threadIdx.x;
  float v = num[l] - den[l];
  for (int d = 1; d < 64; d <<= 1) v += __shfl_xor(v, d);
  if (l == 0) out[BB*SS] = -v;
}

extern "C" void kernel_launch(void* const* d_in, const int* in_sizes, int n_in,
                              void* d_out, int out_size, void* d_ws, size_t ws_size,
                              hipStream_t stream)
{
  const int*   seq       = (const int*)  d_in[0];
  const int*   mask      = (const int*)  d_in[1];
  const int*   labels    = (const int*)  d_in[2];
  const float* embedding = (const float*)d_in[3];
  const float* Wih_f     = (const float*)d_in[4];
  const float* Whh_f     = (const float*)d_in[5];
  const float* bih_f     = (const float*)d_in[6];
  const float* bhh_f     = (const float*)d_in[7];
  const float* Wih_b     = (const float*)d_in[8];
  const float* Whh_b     = (const float*)d_in[9];
  const float* bih_b     = (const float*)d_in[10];
  const float* bhh_b     = (const float*)d_in[11];
  const float* fcW       = (const float*)d_in[12];
  const float* fcb       = (const float*)d_in[13];
  const float* start_t   = (const float*)d_in[14];
  const float* end_t     = (const float*)d_in[15];
  const float* trans     = (const float*)d_in[16];

  char* ws = (char*)d_ws;
  size_t off = 0;
  unsigned short* gxb = (unsigned short*)(ws + off); off += (size_t)2*SS*1024*64*2;     // 128 MiB
  unsigned short* hf  = (unsigned short*)(ws + off); off += (size_t)(SS+1)*BB*HH*2;     // 16 MiB
  unsigned short* hb  = (unsigned short*)(ws + off); off += (size_t)(SS+1)*BB*HH*2;     // 16 MiB
  float*          lgt = (float*)(ws + off);          off += (size_t)SS*BB*TT*4;         // 4 MiB
  unsigned char*  vh  = (unsigned char*)(ws + off);  off += (size_t)SS*BB*TT;           // 1 MiB
  float*          den = (float*)(ws + off);          off += 256;
  float*          num = (float*)(ws + off);          off += 256;

  hipMemsetAsync(hf, 0, (size_t)BB*HH*2, stream);
  hipMemsetAsync(hb + (size_t)SS*BB*HH, 0, (size_t)BB*HH*2, stream);

  k_xgemm<<<dim3(256,2), 256, 0, stream>>>(seq, embedding, Wih_f, Wih_b, gxb);
  k_lstm<<<8, 512, 0, stream>>>(gxb, Whh_f, bih_f, bhh_f, Whh_b, bih_b, bhh_b, hf, hb);
  k_fc<<<256, 256, 0, stream>>>(hf, hb, fcW, fcb, lgt);
  k_crf<<<48, 256, 0, stream>>>(lgt, mask, labels, start_t, end_t, trans, den, num, vh, (float*)d_out);
  k_loss<<<1, 64, 0, stream>>>(num, den, (float*)d_out);
}

// Round 7
// 1900.041 us; speedup vs baseline: 1.7158x; 1.7158x over previous
//
#include <hip/hip_runtime.h>
#include <stdint.h>

#define SS 512
#define BB 64
#define HH 256
#define TT 32

typedef __attribute__((ext_vector_type(8))) short bf16x8;
typedef __attribute__((ext_vector_type(4))) short short4v;
typedef __attribute__((ext_vector_type(4))) float f32x4;
typedef __attribute__((ext_vector_type(2))) float f32x2;

__device__ __forceinline__ unsigned short f2bf(float f){
  unsigned u = __float_as_uint(f);
  unsigned r = (u + 0x7FFFu + ((u >> 16) & 1u)) >> 16;
  return (unsigned short)r;
}
__device__ __forceinline__ float bf2f(unsigned short s){
  return __uint_as_float(((unsigned)s) << 16);
}
__device__ __forceinline__ float sigm(float x){ return 1.0f/(1.0f+__expf(-x)); }
__device__ __forceinline__ float ftanh(float x){
  float e = __expf(2.f*x);
  return 1.f - 2.f/(e + 1.f);
}
__device__ __forceinline__ unsigned cvt4fp8(float a0, float a1, float a2, float a3){
  int d = __builtin_amdgcn_cvt_pk_fp8_f32(a0, a1, 0, false);
  d = __builtin_amdgcn_cvt_pk_fp8_f32(a2, a3, d, true);
  return (unsigned)d;
}
__device__ __forceinline__ unsigned short cvt2fp8(float a0, float a1){
  int d = __builtin_amdgcn_cvt_pk_fp8_f32(a0, a1, 0, false);
  return (unsigned short)(d & 0xFFFF);
}

// swizzled-LDS fragment read (used by k_xgemm only)
__device__ __forceinline__ bf16x8 afrag(const unsigned short* A, int mt, int ktp, int nl, int kq){
  int m = mt*16 + nl;
  int sw = (m & 7) << 3;
  int kk = ktp*32 + kq*4;
  short4v lo = *(const short4v*)(A + (m << 8) + (kk ^ sw));
  short4v hi = *(const short4v*)(A + (m << 8) + ((kk + 16) ^ sw));
  bf16x8 r = {lo[0],lo[1],lo[2],lo[3],hi[0],hi[1],hi[2],hi[3]};
  return r;
}

// fp8 A-tile byte position for h-index k (matches B-frag k-map: elems 0-3 <-> k=kt*32+kq*4+j, 4-7 <-> +16)
__device__ __forceinline__ int h8byte(int c){
  return (c >> 5)*32 + ((c & 15) >> 2)*8 + ((c & 16) ? 4 : 0) + (c & 3);
}

// ---------------- fused gather + x@Wih^T GEMM -> gx bf16 [dir*16+bg][t][col(1024)][b(4)] ----------------
__global__ __launch_bounds__(256,1) void k_xgemm(
    const int* __restrict__ seq, const float* __restrict__ emb,
    const float* __restrict__ Wih_f, const float* __restrict__ Wih_b,
    unsigned short* __restrict__ gx)
{
  __shared__ __align__(16) unsigned short A_l[128*256];  // 64 KiB
  __shared__ __align__(16) unsigned short B_l[64*256];   // 32 KiB

  const int tid = threadIdx.x;
  const int lane = tid & 63, w = tid >> 6;
  const int nl = lane & 15, kq = lane >> 4;
  const int pbase = blockIdx.x * 128;
  const int dir = blockIdx.y;
  const float* Wih = dir ? Wih_b : Wih_f;

#pragma unroll
  for (int i = 0; i < 16; ++i){
    int c = tid + i*256;
    int m = c >> 5, k8 = c & 31;
    int p = pbase + m, t = p >> 6, b = p & 63;
    int er = seq[b*SS + t];
    const float* s = emb + (size_t)er*HH + k8*8;
    float4 x0 = *(const float4*)s, x1 = *(const float4*)(s+4);
    union { unsigned short u[8]; uint4 v; } o;
    o.u[0]=f2bf(x0.x); o.u[1]=f2bf(x0.y); o.u[2]=f2bf(x0.z); o.u[3]=f2bf(x0.w);
    o.u[4]=f2bf(x1.x); o.u[5]=f2bf(x1.y); o.u[6]=f2bf(x1.z); o.u[7]=f2bf(x1.w);
    *(uint4*)&A_l[(m << 8) + ((k8*8) ^ ((m & 7) << 3))] = o.v;
  }

  for (int nb = 0; nb < 16; ++nb){
    __syncthreads();
#pragma unroll
    for (int i = 0; i < 8; ++i){
      int c = tid + i*256;
      int m = c >> 5, k8 = c & 31;
      const float* s = Wih + (size_t)(nb*64 + m)*HH + k8*8;
      float4 x0 = *(const float4*)s, x1 = *(const float4*)(s+4);
      union { unsigned short u[8]; uint4 v; } o;
      o.u[0]=f2bf(x0.x); o.u[1]=f2bf(x0.y); o.u[2]=f2bf(x0.z); o.u[3]=f2bf(x0.w);
      o.u[4]=f2bf(x1.x); o.u[5]=f2bf(x1.y); o.u[6]=f2bf(x1.z); o.u[7]=f2bf(x1.w);
      *(uint4*)&B_l[(m << 8) + ((k8*8) ^ ((m & 7) << 3))] = o.v;
    }
    __syncthreads();

    f32x4 acc[2][4];
#pragma unroll
    for (int mt = 0; mt < 2; ++mt)
#pragma unroll
      for (int nt = 0; nt < 4; ++nt) acc[mt][nt] = (f32x4){0.f,0.f,0.f,0.f};

#pragma unroll
    for (int kt = 0; kt < 8; ++kt){
      bf16x8 a0 = afrag(A_l, w*2+0, kt, nl, kq);
      bf16x8 a1 = afrag(A_l, w*2+1, kt, nl, kq);
#pragma unroll
      for (int nt = 0; nt < 4; ++nt){
        bf16x8 bv = afrag(B_l, nt, kt, nl, kq);
        acc[0][nt] = __builtin_amdgcn_mfma_f32_16x16x32_bf16(a0, bv, acc[0][nt], 0,0,0);
        acc[1][nt] = __builtin_amdgcn_mfma_f32_16x16x32_bf16(a1, bv, acc[1][nt], 0,0,0);
      }
    }

    // store: rows r=0..3 are consecutive batches -> gx[(dir*16+bg)][t][col][b4]
#pragma unroll
    for (int mt = 0; mt < 2; ++mt)
#pragma unroll
      for (int nt = 0; nt < 4; ++nt){
        int p0 = pbase + w*32 + mt*16 + kq*4;
        int t = p0 >> 6, b0 = p0 & 63;
        int col = nb*64 + nt*16 + nl;
        union { unsigned short u[4]; uint2 v; } o;
        o.u[0]=f2bf(acc[mt][nt][0]); o.u[1]=f2bf(acc[mt][nt][1]);
        o.u[2]=f2bf(acc[mt][nt][2]); o.u[3]=f2bf(acc[mt][nt][3]);
        *(uint2*)(gx + ((size_t)(dir*16 + (b0 >> 2))*SS + t)*4096 + col*4) = o.v;
      }
  }
}

// ---------------- batch-partitioned bidirectional LSTM, 32 blocks, zero cross-CU comm ----------------
// Block: dir = blk>>4, bg = blk&15 -> batch rows bg*4..+3. 512 threads.
// Wave w: per gate g, gate-cols g*256 + w*32 .. +31 (2 n-tiles). Whh fp8 in VGPRs (128/lane).
// MFMA A = fp8 h tile (rows 0..3 = batch, rows 4..15 = zero). Gate exchange via f32 LDS;
// all 512 threads combine 2 h-values each, writing fp8 next-tile + bf16 global.
#define WSC 64.0f
#define HSC 16.0f
#define ISC (1.0f/(WSC*HSC))

__global__ __launch_bounds__(512,1) void k_lstm(
    const unsigned short* __restrict__ gx,
    const float* __restrict__ Whh_f, const float* __restrict__ bih_f, const float* __restrict__ bhh_f,
    const float* __restrict__ Whh_b, const float* __restrict__ bih_b, const float* __restrict__ bhh_b,
    unsigned short* __restrict__ hf, unsigned short* __restrict__ hb)
{
  __shared__ __align__(16) unsigned char h8[2][16][272];  // fp8 h A-tile, double-buffered
  __shared__ __align__(16) float g_lds[4][4][260];        // gate exchange [gate][b][col]

  const int tid  = threadIdx.x;
  const int lane = tid & 63;
  const int w    = tid >> 6;           // 0..7
  const int nl   = lane & 15;
  const int kq   = lane >> 4;
  const int dir  = blockIdx.x >> 4;
  const int bg   = blockIdx.x & 15;    // batch group (4 rows)

  const float* Whh = dir ? Whh_b : Whh_f;
  const float* bih = dir ? bih_b : bih_f;
  const float* bhh = dir ? bhh_b : bhh_f;
  unsigned short* hbuf = dir ? hb : hf;
  const unsigned short* gxd = gx + (size_t)(dir*16 + bg)*SS*4096;

  // Whh -> fp8 B-fragments in VGPRs: wB[gate][q][kt] (128 VGPR/lane, no spill at launch_bounds(512,1))
  long wB[4][2][8];
#pragma unroll
  for (int g = 0; g < 4; ++g)
#pragma unroll
    for (int q = 0; q < 2; ++q)
#pragma unroll
      for (int kt = 0; kt < 8; ++kt){
        int ncol = g*256 + w*32 + q*16 + nl;
        const float* p = Whh + (size_t)ncol*HH + kt*32 + kq*4;
        float4 lo = *(const float4*)p;
        float4 hi = *(const float4*)(p + 16);
        union { unsigned d[2]; long l; } u;
        u.d[0] = cvt4fp8(lo.x*WSC, lo.y*WSC, lo.z*WSC, lo.w*WSC);
        u.d[1] = cvt4fp8(hi.x*WSC, hi.y*WSC, hi.z*WSC, hi.w*WSC);
        wB[g][q][kt] = u.l;
      }

  // combine-thread mapping: batch b, cols cc, cc+1
  const int cb = tid >> 7;            // 0..3
  const int cc = (tid & 127) * 2;     // 0..254
  float bias_c[4][2];
#pragma unroll
  for (int g = 0; g < 4; ++g)
#pragma unroll
    for (int j = 0; j < 2; ++j){
      int col = g*256 + cc + j;
      bias_c[g][j] = bih[col] + bhh[col];
    }

  // zero both h8 buffers (rows 4..15 stay zero forever -> D rows 4..15 are zero, unread)
  for (int i = tid; i < 2176; i += 512) ((unsigned*)h8)[i] = 0;
  __syncthreads();

  float c0 = 0.f, c1 = 0.f;

  // gx prefetch regs (double-buffered one step ahead)
  unsigned short gxc[4][2], gxn[4][2];
  {
    const int t0 = dir ? (SS-1) : 0;
    const unsigned short* gp = gxd + (size_t)t0*4096;
#pragma unroll
    for (int g = 0; g < 4; ++g)
#pragma unroll
      for (int j = 0; j < 2; ++j)
        gxc[g][j] = gp[(g*256 + cc + j)*4 + cb];
  }

  for (int s = 0; s < SS; ++s){
    const int t = dir ? (SS-1-s) : s;

    // A-fragments from current fp8 tile
    const unsigned char* tp = &h8[s & 1][0][0];
    long af[8];
#pragma unroll
    for (int kt = 0; kt < 8; ++kt)
      af[kt] = *(const long*)(tp + nl*272 + kt*32 + kq*8);

    f32x4 acc[4][2];
#pragma unroll
    for (int g = 0; g < 4; ++g)
#pragma unroll
      for (int q = 0; q < 2; ++q) acc[g][q] = (f32x4){0.f,0.f,0.f,0.f};

#pragma unroll
    for (int kt = 0; kt < 8; ++kt)
#pragma unroll
      for (int g = 0; g < 4; ++g)
#pragma unroll
        for (int q = 0; q < 2; ++q)
          acc[g][q] = __builtin_amdgcn_mfma_f32_16x16x32_fp8_fp8(af[kt], wB[g][q][kt], acc[g][q], 0,0,0);

    // publish real rows (kq==0 holds batch rows 0..3) to gate-exchange LDS
    if (kq == 0){
#pragma unroll
      for (int g = 0; g < 4; ++g)
#pragma unroll
        for (int q = 0; q < 2; ++q)
#pragma unroll
          for (int r = 0; r < 4; ++r)
            g_lds[g][r][w*32 + q*16 + nl] = acc[g][q][r];
    }
    __syncthreads();

    // prefetch gx for next step (hides HBM latency under combine + next MFMA)
    {
      int sn = s + 1;
      int tn = (sn < SS) ? (dir ? (SS-1-sn) : sn) : t;
      const unsigned short* gp = gxd + (size_t)tn*4096;
#pragma unroll
      for (int g = 0; g < 4; ++g)
#pragma unroll
        for (int j = 0; j < 2; ++j)
          gxn[g][j] = gp[(g*256 + cc + j)*4 + cb];
    }

    // combine: all 512 threads, 2 h-values each (batch cb, cols cc..cc+1)
    {
      f32x2 ig = *(const f32x2*)&g_lds[0][cb][cc];
      f32x2 fg = *(const f32x2*)&g_lds[1][cb][cc];
      f32x2 gg = *(const f32x2*)&g_lds[2][cb][cc];
      f32x2 og = *(const f32x2*)&g_lds[3][cb][cc];
      float h0, h1;
      {
        float iv = ig[0]*ISC + bf2f(gxc[0][0]) + bias_c[0][0];
        float fv = fg[0]*ISC + bf2f(gxc[1][0]) + bias_c[1][0];
        float gv = gg[0]*ISC + bf2f(gxc[2][0]) + bias_c[2][0];
        float ov = og[0]*ISC + bf2f(gxc[3][0]) + bias_c[3][0];
        float cnew = sigm(fv)*c0 + sigm(iv)*ftanh(gv);
        c0 = cnew; h0 = sigm(ov)*ftanh(cnew);
      }
      {
        float iv = ig[1]*ISC + bf2f(gxc[0][1]) + bias_c[0][1];
        float fv = fg[1]*ISC + bf2f(gxc[1][1]) + bias_c[1][1];
        float gv = gg[1]*ISC + bf2f(gxc[2][1]) + bias_c[2][1];
        float ov = og[1]*ISC + bf2f(gxc[3][1]) + bias_c[3][1];
        float cnew = sigm(fv)*c1 + sigm(iv)*ftanh(gv);
        c1 = cnew; h1 = sigm(ov)*ftanh(cnew);
      }
      // bf16 h to global (for k_fc)
      const int wslot = dir ? t : (s + 1);
      unsigned hv = ((unsigned)f2bf(h1) << 16) | f2bf(h0);
      *(unsigned*)(hbuf + (size_t)(wslot*BB + bg*4 + cb)*HH + cc) = hv;
      // fp8 h into next A-tile (byte-exact frag packing)
      *(unsigned short*)&h8[(s + 1) & 1][cb][h8byte(cc)] = cvt2fp8(h0*HSC, h1*HSC);
    }

#pragma unroll
    for (int g = 0; g < 4; ++g)
#pragma unroll
      for (int j = 0; j < 2; ++j) gxc[g][j] = gxn[g][j];

    __syncthreads();
  }
}

// ---------------- FC via MFMA: logits[p][tag] = [hf(t+1);hb(t)] . fcW[tag] + fcb ----------------
__global__ __launch_bounds__(256,1) void k_fc(
    const unsigned short* __restrict__ hf, const unsigned short* __restrict__ hb,
    const float* __restrict__ fcW, const float* __restrict__ fcb,
    float* __restrict__ logits)
{
  __shared__ unsigned short Bs[32][520];
  __shared__ float fcb_s[32];
  const int tid = threadIdx.x;
  for (int i = tid; i < 32*512; i += 256){
    int tg = i >> 9, k = i & 511;
    Bs[tg][k] = f2bf(fcW[tg*512 + k]);
  }
  if (tid < 32) fcb_s[tid] = fcb[tid];
  __syncthreads();

  const int lane = tid & 63, w = tid >> 6;
  const int nl = lane & 15, kq = lane >> 4;
  const int pbase = blockIdx.x * 128;

  f32x4 acc[2][2];
#pragma unroll
  for (int mt = 0; mt < 2; ++mt)
#pragma unroll
    for (int nt = 0; nt < 2; ++nt) acc[mt][nt] = (f32x4){0.f,0.f,0.f,0.f};

#pragma unroll
  for (int kt = 0; kt < 16; ++kt){
    int k0 = kt*32 + kq*4;
    bf16x8 a[2];
#pragma unroll
    for (int mt = 0; mt < 2; ++mt){
      int p = pbase + w*32 + mt*16 + nl;
      int t = p >> 6, b = p & 63;
      const unsigned short* hrp = (kt < 8)
        ? hf + (size_t)((t+1)*BB + b)*HH + k0
        : hb + (size_t)(t*BB + b)*HH + (k0 - 256);
      short4v lo = *(const short4v*)hrp;
      short4v hi = *(const short4v*)(hrp + 16);
      bf16x8 f = {lo[0],lo[1],lo[2],lo[3],hi[0],hi[1],hi[2],hi[3]};
      a[mt] = f;
    }
#pragma unroll
    for (int nt = 0; nt < 2; ++nt){
      const unsigned short* br = &Bs[nt*16 + nl][k0];
      short4v lo = *(const short4v*)br;
      short4v hi = *(const short4v*)(br + 16);
      bf16x8 bv = {lo[0],lo[1],lo[2],lo[3],hi[0],hi[1],hi[2],hi[3]};
      acc[0][nt] = __builtin_amdgcn_mfma_f32_16x16x32_bf16(a[0], bv, acc[0][nt], 0,0,0);
      acc[1][nt] = __builtin_amdgcn_mfma_f32_16x16x32_bf16(a[1], bv, acc[1][nt], 0,0,0);
    }
  }
#pragma unroll
  for (int mt = 0; mt < 2; ++mt)
#pragma unroll
    for (int nt = 0; nt < 2; ++nt)
#pragma unroll
      for (int r = 0; r < 4; ++r){
        int p = pbase + w*32 + mt*16 + kq*4 + r;
        int tg = nt*16 + nl;
        logits[(size_t)p*TT + tg] = acc[mt][nt][r] + fcb_s[tg];
      }
}

// ---------------- merged CRF: blocks 0-15 den, 16-31 vit, 32-47 num ----------------
__global__ void k_crf(const float* __restrict__ logits, const int* __restrict__ mask,
                      const int* __restrict__ labels,
                      const float* __restrict__ start, const float* __restrict__ endt,
                      const float* __restrict__ trans,
                      float* __restrict__ den, float* __restrict__ num,
                      unsigned char* __restrict__ vhist, float* __restrict__ preds)
{
  __shared__ float tr[1024];
  const int tid = threadIdx.x;
  const int role = blockIdx.x >> 4;
  const int bq   = blockIdx.x & 15;
  if (role != 2){
    for (int i = tid; i < 1024; i += 256) tr[i] = trans[i];
    __syncthreads();
  }
  const int lane = tid & 63, w = tid >> 6;
  const int b = bq*4 + w;
  const int grp = lane >> 5, tp = lane & 31;

  if (role == 0){ // denominator
    float score = start[tp] + logits[(size_t)b*TT + tp];
    for (int s = 1; s < SS; ++s){
      float m = -1e30f;
#pragma unroll
      for (int jj = 0; jj < 16; ++jj){
        int j = grp*16 + jj;
        float v = __shfl(score, j) + tr[j*32 + tp];
        m = fmaxf(m, v);
      }
      m = fmaxf(m, __shfl_xor(m, 32));
      float ssum = 0.f;
#pragma unroll
      for (int jj = 0; jj < 16; ++jj){
        int j = grp*16 + jj;
        float v = __shfl(score, j) + tr[j*32 + tp];
        ssum += __expf(v - m);
      }
      ssum += __shfl_xor(ssum, 32);
      float ns = m + __logf(ssum) + logits[(size_t)(s*BB + b)*TT + tp];
      score = mask[b*SS + s] ? ns : score;
    }
    float v = score + endt[tp];
    float mm = v;
    for (int d = 1; d < 32; d <<= 1) mm = fmaxf(mm, __shfl_xor(mm, d));
    float se = __expf(v - mm);
    for (int d = 1; d < 32; d <<= 1) se += __shfl_xor(se, d);
    if (lane == 0) den[b] = mm + __logf(se);
  } else if (role == 1){ // viterbi
    float score = start[tp] + logits[(size_t)b*TT + tp];
    for (int s = 1; s < SS; ++s){
      float m = -1e30f; int am = 0;
#pragma unroll
      for (int jj = 0; jj < 16; ++jj){
        int j = grp*16 + jj;
        float v = __shfl(score, j) + tr[j*32 + tp];
        if (v > m){ m = v; am = j; }
      }
      float om = __shfl_xor(m, 32); int oam = __shfl_xor(am, 32);
      if (om > m || (om == m && oam < am)){ m = om; am = oam; }
      int mk = mask[b*SS + s];
      float ns = m + logits[(size_t)(s*BB + b)*TT + tp];
      int idx = mk ? am : tp;
      if (grp == 0) vhist[(size_t)(s*BB + b)*32 + tp] = (unsigned char)idx;
      score = mk ? ns : score;
    }
    float v = score + endt[tp]; int a = tp;
    for (int d = 1; d < 32; d <<= 1){
      float ov = __shfl_xor(v, d); int oa = __shfl_xor(a, d);
      if (ov > v || (ov == v && oa < a)){ v = ov; a = oa; }
    }
    int tag = __shfl(a, 0);
    if (lane == 0) preds[(size_t)b*SS + SS - 1] = (float)tag;
    for (int s = SS - 1; s >= 1; --s){
      int rv = vhist[(size_t)(s*BB + b)*32 + tp];
      int pv = __shfl(rv, tag);
      if (lane == 0) preds[(size_t)b*SS + s - 1] = (float)pv;
      tag = pv;
    }
  } else { // numerator
    float acc = 0.f; int mcnt = 0;
    for (int s = lane; s < SS; s += 64){
      int mk = mask[b*SS + s];
      mcnt += mk;
      if (s >= 1){
        int tg = labels[b*SS + s], tpp = labels[b*SS + s - 1];
        float v = trans[tpp*32 + tg] + logits[(size_t)(s*BB + b)*TT + tg];
        acc += mk ? v : 0.f;
      }
    }
    for (int d = 1; d < 64; d <<= 1){ acc += __shfl_xor(acc, d); mcnt += __shfl_xor(mcnt, d); }
    if (lane == 0){
      int t0 = labels[b*SS];
      int tl = labels[b*SS + (mcnt - 1)];
      num[b] = start[t0] + logits[(size_t)b*TT + t0] + acc + endt[tl];
    }
  }
}

// ---------------- loss ----------------
__global__ void k_loss(const float* __restrict__ num, const float* __restrict__ den,
                       float* __restrict__ out)
{
  int l = threadIdx.x;
  float v = num[l] - den[l];
  for (int d = 1; d < 64; d <<= 1) v += __shfl_xor(v, d);
  if (l == 0) out[BB*SS] = -v;
}

extern "C" void kernel_launch(void* const* d_in, const int* in_sizes, int n_in,
                              void* d_out, int out_size, void* d_ws, size_t ws_size,
                              hipStream_t stream)
{
  const int*   seq       = (const int*)  d_in[0];
  const int*   mask      = (const int*)  d_in[1];
  const int*   labels    = (const int*)  d_in[2];
  const float* embedding = (const float*)d_in[3];
  const float* Wih_f     = (const float*)d_in[4];
  const float* Whh_f     = (const float*)d_in[5];
  const float* bih_f     = (const float*)d_in[6];
  const float* bhh_f     = (const float*)d_in[7];
  const float* Wih_b     = (const float*)d_in[8];
  const float* Whh_b     = (const float*)d_in[9];
  const float* bih_b     = (const float*)d_in[10];
  const float* bhh_b     = (const float*)d_in[11];
  const float* fcW       = (const float*)d_in[12];
  const float* fcb       = (const float*)d_in[13];
  const float* start_t   = (const float*)d_in[14];
  const float* end_t     = (const float*)d_in[15];
  const float* trans     = (const float*)d_in[16];

  char* ws = (char*)d_ws;
  size_t off = 0;
  unsigned short* gxb = (unsigned short*)(ws + off); off += (size_t)2*SS*1024*64*2;     // 128 MiB
  unsigned short* hf  = (unsigned short*)(ws + off); off += (size_t)(SS+1)*BB*HH*2;     // 16 MiB
  unsigned short* hb  = (unsigned short*)(ws + off); off += (size_t)(SS+1)*BB*HH*2;     // 16 MiB
  float*          lgt = (float*)(ws + off);          off += (size_t)SS*BB*TT*4;         // 4 MiB
  unsigned char*  vh  = (unsigned char*)(ws + off);  off += (size_t)SS*BB*TT;           // 1 MiB
  float*          den = (float*)(ws + off);          off += 256;
  float*          num = (float*)(ws + off);          off += 256;

  k_xgemm<<<dim3(256,2), 256, 0, stream>>>(seq, embedding, Wih_f, Wih_b, gxb);
  k_lstm<<<32, 512, 0, stream>>>(gxb, Whh_f, bih_f, bhh_f, Whh_b, bih_b, bhh_b, hf, hb);
  k_fc<<<256, 256, 0, stream>>>(hf, hb, fcW, fcb, lgt);
  k_crf<<<48, 256, 0, stream>>>(lgt, mask, labels, start_t, end_t, trans, den, num, vh, (float*)d_out);
  k_loss<<<1, 64, 0, stream>>>(num, den, (float*)d_out);
}

// Round 8
// 1875.569 us; speedup vs baseline: 1.7382x; 1.0130x over previous
//
#include <hip/hip_runtime.h>
#include <stdint.h>

#define SS 512
#define BB 64
#define HH 256
#define TT 32

typedef __attribute__((ext_vector_type(8))) short bf16x8;
typedef __attribute__((ext_vector_type(4))) short short4v;
typedef __attribute__((ext_vector_type(4))) float f32x4;
typedef __attribute__((ext_vector_type(2))) float f32x2;

__device__ __forceinline__ unsigned short f2bf(float f){
  unsigned u = __float_as_uint(f);
  unsigned r = (u + 0x7FFFu + ((u >> 16) & 1u)) >> 16;
  return (unsigned short)r;
}
__device__ __forceinline__ float bf2f(unsigned short s){
  return __uint_as_float(((unsigned)s) << 16);
}
__device__ __forceinline__ float sigm(float x){ return 1.0f/(1.0f+__expf(-x)); }
__device__ __forceinline__ float ftanh(float x){
  float e = __expf(2.f*x);
  return 1.f - 2.f/(e + 1.f);
}
__device__ __forceinline__ unsigned cvt4fp8(float a0, float a1, float a2, float a3){
  int d = __builtin_amdgcn_cvt_pk_fp8_f32(a0, a1, 0, false);
  d = __builtin_amdgcn_cvt_pk_fp8_f32(a2, a3, d, true);
  return (unsigned)d;
}

// swizzled-LDS fragment read (used by k_xgemm only)
__device__ __forceinline__ bf16x8 afrag(const unsigned short* A, int mt, int ktp, int nl, int kq){
  int m = mt*16 + nl;
  int sw = (m & 7) << 3;
  int kk = ktp*32 + kq*4;
  short4v lo = *(const short4v*)(A + (m << 8) + (kk ^ sw));
  short4v hi = *(const short4v*)(A + (m << 8) + ((kk + 16) ^ sw));
  bf16x8 r = {lo[0],lo[1],lo[2],lo[3],hi[0],hi[1],hi[2],hi[3]};
  return r;
}

// ---------------- fused gather + x@Wih^T GEMM -> gx bf16 [dir*16+bg][t][col(1024)][b(4)] ----------------
__global__ __launch_bounds__(256,1) void k_xgemm(
    const int* __restrict__ seq, const float* __restrict__ emb,
    const float* __restrict__ Wih_f, const float* __restrict__ Wih_b,
    unsigned short* __restrict__ gx)
{
  __shared__ __align__(16) unsigned short A_l[128*256];  // 64 KiB
  __shared__ __align__(16) unsigned short B_l[64*256];   // 32 KiB

  const int tid = threadIdx.x;
  const int lane = tid & 63, w = tid >> 6;
  const int nl = lane & 15, kq = lane >> 4;
  const int pbase = blockIdx.x * 128;
  const int dir = blockIdx.y;
  const float* Wih = dir ? Wih_b : Wih_f;

#pragma unroll
  for (int i = 0; i < 16; ++i){
    int c = tid + i*256;
    int m = c >> 5, k8 = c & 31;
    int p = pbase + m, t = p >> 6, b = p & 63;
    int er = seq[b*SS + t];
    const float* s = emb + (size_t)er*HH + k8*8;
    float4 x0 = *(const float4*)s, x1 = *(const float4*)(s+4);
    union { unsigned short u[8]; uint4 v; } o;
    o.u[0]=f2bf(x0.x); o.u[1]=f2bf(x0.y); o.u[2]=f2bf(x0.z); o.u[3]=f2bf(x0.w);
    o.u[4]=f2bf(x1.x); o.u[5]=f2bf(x1.y); o.u[6]=f2bf(x1.z); o.u[7]=f2bf(x1.w);
    *(uint4*)&A_l[(m << 8) + ((k8*8) ^ ((m & 7) << 3))] = o.v;
  }

  for (int nb = 0; nb < 16; ++nb){
    __syncthreads();
#pragma unroll
    for (int i = 0; i < 8; ++i){
      int c = tid + i*256;
      int m = c >> 5, k8 = c & 31;
      const float* s = Wih + (size_t)(nb*64 + m)*HH + k8*8;
      float4 x0 = *(const float4*)s, x1 = *(const float4*)(s+4);
      union { unsigned short u[8]; uint4 v; } o;
      o.u[0]=f2bf(x0.x); o.u[1]=f2bf(x0.y); o.u[2]=f2bf(x0.z); o.u[3]=f2bf(x0.w);
      o.u[4]=f2bf(x1.x); o.u[5]=f2bf(x1.y); o.u[6]=f2bf(x1.z); o.u[7]=f2bf(x1.w);
      *(uint4*)&B_l[(m << 8) + ((k8*8) ^ ((m & 7) << 3))] = o.v;
    }
    __syncthreads();

    f32x4 acc[2][4];
#pragma unroll
    for (int mt = 0; mt < 2; ++mt)
#pragma unroll
      for (int nt = 0; nt < 4; ++nt) acc[mt][nt] = (f32x4){0.f,0.f,0.f,0.f};

#pragma unroll
    for (int kt = 0; kt < 8; ++kt){
      bf16x8 a0 = afrag(A_l, w*2+0, kt, nl, kq);
      bf16x8 a1 = afrag(A_l, w*2+1, kt, nl, kq);
#pragma unroll
      for (int nt = 0; nt < 4; ++nt){
        bf16x8 bv = afrag(B_l, nt, kt, nl, kq);
        acc[0][nt] = __builtin_amdgcn_mfma_f32_16x16x32_bf16(a0, bv, acc[0][nt], 0,0,0);
        acc[1][nt] = __builtin_amdgcn_mfma_f32_16x16x32_bf16(a1, bv, acc[1][nt], 0,0,0);
      }
    }

    // store: rows r=0..3 are consecutive batches -> gx[(dir*16+bg)][t][col][b4]
#pragma unroll
    for (int mt = 0; mt < 2; ++mt)
#pragma unroll
      for (int nt = 0; nt < 4; ++nt){
        int p0 = pbase + w*32 + mt*16 + kq*4;
        int t = p0 >> 6, b0 = p0 & 63;
        int col = nb*64 + nt*16 + nl;
        union { unsigned short u[4]; uint2 v; } o;
        o.u[0]=f2bf(acc[mt][nt][0]); o.u[1]=f2bf(acc[mt][nt][1]);
        o.u[2]=f2bf(acc[mt][nt][2]); o.u[3]=f2bf(acc[mt][nt][3]);
        *(uint2*)(gx + ((size_t)(dir*16 + (b0 >> 2))*SS + t)*4096 + col*4) = o.v;
      }
  }
}

// ---------------- batch-partitioned bidirectional LSTM, 32 blocks, zero cross-CU comm ----------------
// Block: dir = blk>>4, bg = blk&15 -> batch rows bg*4..+3. 512 threads.
// fp8 Whh resident in regs (128/lane). MFMA A-tile rebuilt per-lane each step from an
// f32 h*HSC staging LDS (conflict-free); combine thread = (hcol, 2 batches) with ONE
// coalesced dword gx load per gate.
#define WSC 64.0f
#define HSC 16.0f
#define ISC (1.0f/(WSC*HSC))

__global__ __launch_bounds__(512,1) void k_lstm(
    const unsigned short* __restrict__ gx,
    const float* __restrict__ Whh_f, const float* __restrict__ bih_f, const float* __restrict__ bhh_f,
    const float* __restrict__ Whh_b, const float* __restrict__ bih_b, const float* __restrict__ bhh_b,
    unsigned short* __restrict__ hf, unsigned short* __restrict__ hb)
{
  __shared__ __align__(16) float hst[2][4][264];    // h*HSC f32 staging (double-buffered)
  __shared__ __align__(16) float g_lds[4][4][260];  // gate exchange [gate][b][col]

  const int tid  = threadIdx.x;
  const int lane = tid & 63;
  const int w    = tid >> 6;           // 0..7
  const int nl   = lane & 15;
  const int kq   = lane >> 4;
  const int dir  = blockIdx.x >> 4;
  const int bg   = blockIdx.x & 15;    // batch group (4 rows)

  const float* Whh = dir ? Whh_b : Whh_f;
  const float* bih = dir ? bih_b : bih_f;
  const float* bhh = dir ? bhh_b : bhh_f;
  unsigned short* hbuf = dir ? hb : hf;
  const unsigned short* gxd = gx + (size_t)(dir*16 + bg)*SS*4096;

  // Whh -> fp8 B-fragments in VGPRs/AGPRs: wB[gate][q][kt]
  long wB[4][2][8];
#pragma unroll
  for (int g = 0; g < 4; ++g)
#pragma unroll
    for (int q = 0; q < 2; ++q)
#pragma unroll
      for (int kt = 0; kt < 8; ++kt){
        int ncol = g*256 + w*32 + q*16 + nl;
        const float* p = Whh + (size_t)ncol*HH + kt*32 + kq*4;
        float4 lo = *(const float4*)p;
        float4 hi = *(const float4*)(p + 16);
        union { unsigned d[2]; long l; } u;
        u.d[0] = cvt4fp8(lo.x*WSC, lo.y*WSC, lo.z*WSC, lo.w*WSC);
        u.d[1] = cvt4fp8(hi.x*WSC, hi.y*WSC, hi.z*WSC, hi.w*WSC);
        wB[g][q][kt] = u.l;
      }

  // combine-thread mapping: hcol hc, batches bh, bh+1
  const int hc = tid >> 1;            // 0..255
  const int bh = (tid & 1) * 2;       // 0 or 2
  float bias_c[4];
#pragma unroll
  for (int g = 0; g < 4; ++g) bias_c[g] = bih[g*256 + hc] + bhh[g*256 + hc];

  // zero h staging (h_0 = 0), both buffers
  for (int i = tid; i < 2112; i += 512) ((float*)hst)[i] = 0.f;
  __syncthreads();

  float c0 = 0.f, c1 = 0.f;

  // gx prefetch regs: one dword per gate = 2 batches (coalesced 256B/wave)
  union { unsigned v; unsigned short u[2]; } gxc[4], gxn[4];
  {
    const int t0 = dir ? (SS-1) : 0;
    const unsigned short* gp = gxd + (size_t)t0*4096;
#pragma unroll
    for (int g = 0; g < 4; ++g)
      gxc[g].v = *(const unsigned*)(gp + (g*256 + hc)*4 + bh);
  }

  for (int s = 0; s < SS; ++s){
    const int t = dir ? (SS-1-s) : s;

    // A-fragment build: rows nl<4 from f32 staging + in-lane fp8 convert; rows 4..15 zero
    long af[8];
    if (nl < 4){
      const float* rp = &hst[s & 1][nl][0];
#pragma unroll
      for (int kt = 0; kt < 8; ++kt){
        f32x4 lo = *(const f32x4*)(rp + kt*32 + kq*4);
        f32x4 hi = *(const f32x4*)(rp + kt*32 + kq*4 + 16);
        union { unsigned d[2]; long l; } u;
        u.d[0] = cvt4fp8(lo[0], lo[1], lo[2], lo[3]);
        u.d[1] = cvt4fp8(hi[0], hi[1], hi[2], hi[3]);
        af[kt] = u.l;
      }
    } else {
#pragma unroll
      for (int kt = 0; kt < 8; ++kt) af[kt] = 0;
    }

    // prefetch next-step gx early (independent; flies during MFMA)
    {
      int sn = s + 1;
      int tn = (sn < SS) ? (dir ? (SS-1-sn) : sn) : t;
      const unsigned short* gp = gxd + (size_t)tn*4096;
#pragma unroll
      for (int g = 0; g < 4; ++g)
        gxn[g].v = *(const unsigned*)(gp + (g*256 + hc)*4 + bh);
    }

    f32x4 acc[4][2];
#pragma unroll
    for (int g = 0; g < 4; ++g)
#pragma unroll
      for (int q = 0; q < 2; ++q) acc[g][q] = (f32x4){0.f,0.f,0.f,0.f};

#pragma unroll
    for (int kt = 0; kt < 8; ++kt)
#pragma unroll
      for (int g = 0; g < 4; ++g)
#pragma unroll
        for (int q = 0; q < 2; ++q)
          acc[g][q] = __builtin_amdgcn_mfma_f32_16x16x32_fp8_fp8(af[kt], wB[g][q][kt], acc[g][q], 0,0,0);

    // publish real rows (kq==0 holds batch rows 0..3)
    if (kq == 0){
#pragma unroll
      for (int g = 0; g < 4; ++g)
#pragma unroll
        for (int q = 0; q < 2; ++q)
#pragma unroll
          for (int r = 0; r < 4; ++r)
            g_lds[g][r][w*32 + q*16 + nl] = acc[g][q][r];
    }
    __syncthreads();

    // combine: thread (hc, batches bh..bh+1)
    {
      const int wslot = dir ? t : (s + 1);
      float* hn = &hst[(s + 1) & 1][0][0];
      float h[2];
#pragma unroll
      for (int j = 0; j < 2; ++j){
        int b = bh + j;
        float iv = g_lds[0][b][hc]*ISC + bf2f(gxc[0].u[j]) + bias_c[0];
        float fv = g_lds[1][b][hc]*ISC + bf2f(gxc[1].u[j]) + bias_c[1];
        float gv = g_lds[2][b][hc]*ISC + bf2f(gxc[2].u[j]) + bias_c[2];
        float ov = g_lds[3][b][hc]*ISC + bf2f(gxc[3].u[j]) + bias_c[3];
        float cold = j ? c1 : c0;
        float cnew = sigm(fv)*cold + sigm(iv)*ftanh(gv);
        if (j) c1 = cnew; else c0 = cnew;
        h[j] = sigm(ov)*ftanh(cnew);
        hn[b*264 + hc] = h[j]*HSC;
        hbuf[(size_t)(wslot*BB + bg*4 + b)*HH + hc] = (unsigned short)f2bf(h[j]);
      }
    }

#pragma unroll
    for (int g = 0; g < 4; ++g) gxc[g].v = gxn[g].v;

    __syncthreads();
  }
}

// ---------------- FC via MFMA: logits[p][tag] = [hf(t+1);hb(t)] . fcW[tag] + fcb ----------------
__global__ __launch_bounds__(256,1) void k_fc(
    const unsigned short* __restrict__ hf, const unsigned short* __restrict__ hb,
    const float* __restrict__ fcW, const float* __restrict__ fcb,
    float* __restrict__ logits)
{
  __shared__ unsigned short Bs[32][520];
  __shared__ float fcb_s[32];
  const int tid = threadIdx.x;
  for (int i = tid; i < 32*512; i += 256){
    int tg = i >> 9, k = i & 511;
    Bs[tg][k] = f2bf(fcW[tg*512 + k]);
  }
  if (tid < 32) fcb_s[tid] = fcb[tid];
  __syncthreads();

  const int lane = tid & 63, w = tid >> 6;
  const int nl = lane & 15, kq = lane >> 4;
  const int pbase = blockIdx.x * 128;

  f32x4 acc[2][2];
#pragma unroll
  for (int mt = 0; mt < 2; ++mt)
#pragma unroll
    for (int nt = 0; nt < 2; ++nt) acc[mt][nt] = (f32x4){0.f,0.f,0.f,0.f};

#pragma unroll
  for (int kt = 0; kt < 16; ++kt){
    int k0 = kt*32 + kq*4;
    bf16x8 a[2];
#pragma unroll
    for (int mt = 0; mt < 2; ++mt){
      int p = pbase + w*32 + mt*16 + nl;
      int t = p >> 6, b = p & 63;
      const unsigned short* hrp = (kt < 8)
        ? hf + (size_t)((t+1)*BB + b)*HH + k0
        : hb + (size_t)(t*BB + b)*HH + (k0 - 256);
      short4v lo = *(const short4v*)hrp;
      short4v hi = *(const short4v*)(hrp + 16);
      bf16x8 f = {lo[0],lo[1],lo[2],lo[3],hi[0],hi[1],hi[2],hi[3]};
      a[mt] = f;
    }
#pragma unroll
    for (int nt = 0; nt < 2; ++nt){
      const unsigned short* br = &Bs[nt*16 + nl][k0];
      short4v lo = *(const short4v*)br;
      short4v hi = *(const short4v*)(br + 16);
      bf16x8 bv = {lo[0],lo[1],lo[2],lo[3],hi[0],hi[1],hi[2],hi[3]};
      acc[0][nt] = __builtin_amdgcn_mfma_f32_16x16x32_bf16(a[0], bv, acc[0][nt], 0,0,0);
      acc[1][nt] = __builtin_amdgcn_mfma_f32_16x16x32_bf16(a[1], bv, acc[1][nt], 0,0,0);
    }
  }
#pragma unroll
  for (int mt = 0; mt < 2; ++mt)
#pragma unroll
    for (int nt = 0; nt < 2; ++nt)
#pragma unroll
      for (int r = 0; r < 4; ++r){
        int p = pbase + w*32 + mt*16 + kq*4 + r;
        int tg = nt*16 + nl;
        logits[(size_t)p*TT + tg] = acc[mt][nt][r] + fcb_s[tg];
      }
}

// ---------------- merged CRF: blocks 0-15 den, 16-31 vit, 32-47 num ----------------
__global__ void k_crf(const float* __restrict__ logits, const int* __restrict__ mask,
                      const int* __restrict__ labels,
                      const float* __restrict__ start, const float* __restrict__ endt,
                      const float* __restrict__ trans,
                      float* __restrict__ den, float* __restrict__ num,
                      unsigned char* __restrict__ vhist, float* __restrict__ preds)
{
  __shared__ float tr[1024];
  const int tid = threadIdx.x;
  const int role = blockIdx.x >> 4;
  const int bq   = blockIdx.x & 15;
  if (role != 2){
    for (int i = tid; i < 1024; i += 256) tr[i] = trans[i];
    __syncthreads();
  }
  const int lane = tid & 63, w = tid >> 6;
  const int b = bq*4 + w;
  const int grp = lane >> 5, tp = lane & 31;

  if (role == 0){ // denominator
    float score = start[tp] + logits[(size_t)b*TT + tp];
    for (int s = 1; s < SS; ++s){
      float m = -1e30f;
#pragma unroll
      for (int jj = 0; jj < 16; ++jj){
        int j = grp*16 + jj;
        float v = __shfl(score, j) + tr[j*32 + tp];
        m = fmaxf(m, v);
      }
      m = fmaxf(m, __shfl_xor(m, 32));
      float ssum = 0.f;
#pragma unroll
      for (int jj = 0; jj < 16; ++jj){
        int j = grp*16 + jj;
        float v = __shfl(score, j) + tr[j*32 + tp];
        ssum += __expf(v - m);
      }
      ssum += __shfl_xor(ssum, 32);
      float ns = m + __logf(ssum) + logits[(size_t)(s*BB + b)*TT + tp];
      score = mask[b*SS + s] ? ns : score;
    }
    float v = score + endt[tp];
    float mm = v;
    for (int d = 1; d < 32; d <<= 1) mm = fmaxf(mm, __shfl_xor(mm, d));
    float se = __expf(v - mm);
    for (int d = 1; d < 32; d <<= 1) se += __shfl_xor(se, d);
    if (lane == 0) den[b] = mm + __logf(se);
  } else if (role == 1){ // viterbi
    float score = start[tp] + logits[(size_t)b*TT + tp];
    for (int s = 1; s < SS; ++s){
      float m = -1e30f; int am = 0;
#pragma unroll
      for (int jj = 0; jj < 16; ++jj){
        int j = grp*16 + jj;
        float v = __shfl(score, j) + tr[j*32 + tp];
        if (v > m){ m = v; am = j; }
      }
      float om = __shfl_xor(m, 32); int oam = __shfl_xor(am, 32);
      if (om > m || (om == m && oam < am)){ m = om; am = oam; }
      int mk = mask[b*SS + s];
      float ns = m + logits[(size_t)(s*BB + b)*TT + tp];
      int idx = mk ? am : tp;
      if (grp == 0) vhist[(size_t)(s*BB + b)*32 + tp] = (unsigned char)idx;
      score = mk ? ns : score;
    }
    float v = score + endt[tp]; int a = tp;
    for (int d = 1; d < 32; d <<= 1){
      float ov = __shfl_xor(v, d); int oa = __shfl_xor(a, d);
      if (ov > v || (ov == v && oa < a)){ v = ov; a = oa; }
    }
    int tag = __shfl(a, 0);
    if (lane == 0) preds[(size_t)b*SS + SS - 1] = (float)tag;
    for (int s = SS - 1; s >= 1; --s){
      int rv = vhist[(size_t)(s*BB + b)*32 + tp];
      int pv = __shfl(rv, tag);
      if (lane == 0) preds[(size_t)b*SS + s - 1] = (float)pv;
      tag = pv;
    }
  } else { // numerator
    float acc = 0.f; int mcnt = 0;
    for (int s = lane; s < SS; s += 64){
      int mk = mask[b*SS + s];
      mcnt += mk;
      if (s >= 1){
        int tg = labels[b*SS + s], tpp = labels[b*SS + s - 1];
        float v = trans[tpp*32 + tg] + logits[(size_t)(s*BB + b)*TT + tg];
        acc += mk ? v : 0.f;
      }
    }
    for (int d = 1; d < 64; d <<= 1){ acc += __shfl_xor(acc, d); mcnt += __shfl_xor(mcnt, d); }
    if (lane == 0){
      int t0 = labels[b*SS];
      int tl = labels[b*SS + (mcnt - 1)];
      num[b] = start[t0] + logits[(size_t)b*TT + t0] + acc + endt[tl];
    }
  }
}

// ---------------- loss ----------------
__global__ void k_loss(const float* __restrict__ num, const float* __restrict__ den,
                       float* __restrict__ out)
{
  int l = threadIdx.x;
  float v = num[l] - den[l];
  for (int d = 1; d < 64; d <<= 1) v += __shfl_xor(v, d);
  if (l == 0) out[BB*SS] = -v;
}

extern "C" void kernel_launch(void* const* d_in, const int* in_sizes, int n_in,
                              void* d_out, int out_size, void* d_ws, size_t ws_size,
                              hipStream_t stream)
{
  const int*   seq       = (const int*)  d_in[0];
  const int*   mask      = (const int*)  d_in[1];
  const int*   labels    = (const int*)  d_in[2];
  const float* embedding = (const float*)d_in[3];
  const float* Wih_f     = (const float*)d_in[4];
  const float* Whh_f     = (const float*)d_in[5];
  const float* bih_f     = (const float*)d_in[6];
  const float* bhh_f     = (const float*)d_in[7];
  const float* Wih_b     = (const float*)d_in[8];
  const float* Whh_b     = (const float*)d_in[9];
  const float* bih_b     = (const float*)d_in[10];
  const float* bhh_b     = (const float*)d_in[11];
  const float* fcW       = (const float*)d_in[12];
  const float* fcb       = (const float*)d_in[13];
  const float* start_t   = (const float*)d_in[14];
  const float* end_t     = (const float*)d_in[15];
  const float* trans     = (const float*)d_in[16];

  char* ws = (char*)d_ws;
  size_t off = 0;
  unsigned short* gxb = (unsigned short*)(ws + off); off += (size_t)2*SS*1024*64*2;     // 128 MiB
  unsigned short* hf  = (unsigned short*)(ws + off); off += (size_t)(SS+1)*BB*HH*2;     // 16 MiB
  unsigned short* hb  = (unsigned short*)(ws + off); off += (size_t)(SS+1)*BB*HH*2;     // 16 MiB
  float*          lgt = (float*)(ws + off);          off += (size_t)SS*BB*TT*4;         // 4 MiB
  unsigned char*  vh  = (unsigned char*)(ws + off);  off += (size_t)SS*BB*TT;           // 1 MiB
  float*          den = (float*)(ws + off);          off += 256;
  float*          num = (float*)(ws + off);          off += 256;

  k_xgemm<<<dim3(256,2), 256, 0, stream>>>(seq, embedding, Wih_f, Wih_b, gxb);
  k_lstm<<<32, 512, 0, stream>>>(gxb, Whh_f, bih_f, bhh_f, Whh_b, bih_b, bhh_b, hf, hb);
  k_fc<<<256, 256, 0, stream>>>(hf, hb, fcW, fcb, lgt);
  k_crf<<<48, 256, 0, stream>>>(lgt, mask, labels, start_t, end_t, trans, den, num, vh, (float*)d_out);
  k_loss<<<1, 64, 0, stream>>>(num, den, (float*)d_out);
}

// Round 9
// 1739.031 us; speedup vs baseline: 1.8747x; 1.0785x over previous
//
#include <hip/hip_runtime.h>
#include <stdint.h>

#define SS 512
#define BB 64
#define HH 256
#define TT 32

typedef __attribute__((ext_vector_type(8))) short bf16x8;
typedef __attribute__((ext_vector_type(4))) short short4v;
typedef __attribute__((ext_vector_type(4))) float f32x4;

__device__ __forceinline__ unsigned short f2bf(float f){
  unsigned u = __float_as_uint(f);
  unsigned r = (u + 0x7FFFu + ((u >> 16) & 1u)) >> 16;
  return (unsigned short)r;
}
__device__ __forceinline__ float bf2f(unsigned short s){
  return __uint_as_float(((unsigned)s) << 16);
}
__device__ __forceinline__ float sigm(float x){ return 1.0f/(1.0f+__expf(-x)); }
__device__ __forceinline__ float ftanh(float x){
  float e = __expf(2.f*x);
  return 1.f - 2.f/(e + 1.f);
}
__device__ __forceinline__ unsigned cvt4fp8(float a0, float a1, float a2, float a3){
  int d = __builtin_amdgcn_cvt_pk_fp8_f32(a0, a1, 0, false);
  d = __builtin_amdgcn_cvt_pk_fp8_f32(a2, a3, d, true);
  return (unsigned)d;
}
__device__ __forceinline__ unsigned char cvt1fp8(float a){
  int d = __builtin_amdgcn_cvt_pk_fp8_f32(a, a, 0, false);
  return (unsigned char)(d & 0xFF);
}

// swizzled-LDS fragment read (used by k_xgemm only)
__device__ __forceinline__ bf16x8 afrag(const unsigned short* A, int mt, int ktp, int nl, int kq){
  int m = mt*16 + nl;
  int sw = (m & 7) << 3;
  int kk = ktp*32 + kq*4;
  short4v lo = *(const short4v*)(A + (m << 8) + (kk ^ sw));
  short4v hi = *(const short4v*)(A + (m << 8) + ((kk + 16) ^ sw));
  bf16x8 r = {lo[0],lo[1],lo[2],lo[3],hi[0],hi[1],hi[2],hi[3]};
  return r;
}

// ---------------- fused gather + x@Wih^T GEMM -> gx bf16 [dir*16+bg][t][col(1024)][b(4)] ----------------
__global__ __launch_bounds__(256,1) void k_xgemm(
    const int* __restrict__ seq, const float* __restrict__ emb,
    const float* __restrict__ Wih_f, const float* __restrict__ Wih_b,
    unsigned short* __restrict__ gx)
{
  __shared__ __align__(16) unsigned short A_l[128*256];  // 64 KiB
  __shared__ __align__(16) unsigned short B_l[64*256];   // 32 KiB

  const int tid = threadIdx.x;
  const int lane = tid & 63, w = tid >> 6;
  const int nl = lane & 15, kq = lane >> 4;
  const int pbase = blockIdx.x * 128;
  const int dir = blockIdx.y;
  const float* Wih = dir ? Wih_b : Wih_f;

#pragma unroll
  for (int i = 0; i < 16; ++i){
    int c = tid + i*256;
    int m = c >> 5, k8 = c & 31;
    int p = pbase + m, t = p >> 6, b = p & 63;
    int er = seq[b*SS + t];
    const float* s = emb + (size_t)er*HH + k8*8;
    float4 x0 = *(const float4*)s, x1 = *(const float4*)(s+4);
    union { unsigned short u[8]; uint4 v; } o;
    o.u[0]=f2bf(x0.x); o.u[1]=f2bf(x0.y); o.u[2]=f2bf(x0.z); o.u[3]=f2bf(x0.w);
    o.u[4]=f2bf(x1.x); o.u[5]=f2bf(x1.y); o.u[6]=f2bf(x1.z); o.u[7]=f2bf(x1.w);
    *(uint4*)&A_l[(m << 8) + ((k8*8) ^ ((m & 7) << 3))] = o.v;
  }

  for (int nb = 0; nb < 16; ++nb){
    __syncthreads();
#pragma unroll
    for (int i = 0; i < 8; ++i){
      int c = tid + i*256;
      int m = c >> 5, k8 = c & 31;
      const float* s = Wih + (size_t)(nb*64 + m)*HH + k8*8;
      float4 x0 = *(const float4*)s, x1 = *(const float4*)(s+4);
      union { unsigned short u[8]; uint4 v; } o;
      o.u[0]=f2bf(x0.x); o.u[1]=f2bf(x0.y); o.u[2]=f2bf(x0.z); o.u[3]=f2bf(x0.w);
      o.u[4]=f2bf(x1.x); o.u[5]=f2bf(x1.y); o.u[6]=f2bf(x1.z); o.u[7]=f2bf(x1.w);
      *(uint4*)&B_l[(m << 8) + ((k8*8) ^ ((m & 7) << 3))] = o.v;
    }
    __syncthreads();

    f32x4 acc[2][4];
#pragma unroll
    for (int mt = 0; mt < 2; ++mt)
#pragma unroll
      for (int nt = 0; nt < 4; ++nt) acc[mt][nt] = (f32x4){0.f,0.f,0.f,0.f};

#pragma unroll
    for (int kt = 0; kt < 8; ++kt){
      bf16x8 a0 = afrag(A_l, w*2+0, kt, nl, kq);
      bf16x8 a1 = afrag(A_l, w*2+1, kt, nl, kq);
#pragma unroll
      for (int nt = 0; nt < 4; ++nt){
        bf16x8 bv = afrag(B_l, nt, kt, nl, kq);
        acc[0][nt] = __builtin_amdgcn_mfma_f32_16x16x32_bf16(a0, bv, acc[0][nt], 0,0,0);
        acc[1][nt] = __builtin_amdgcn_mfma_f32_16x16x32_bf16(a1, bv, acc[1][nt], 0,0,0);
      }
    }

    // store: rows r=0..3 are consecutive batches -> gx[(dir*16+bg)][t][col][b4]
#pragma unroll
    for (int mt = 0; mt < 2; ++mt)
#pragma unroll
      for (int nt = 0; nt < 4; ++nt){
        int p0 = pbase + w*32 + mt*16 + kq*4;
        int t = p0 >> 6, b0 = p0 & 63;
        int col = nb*64 + nt*16 + nl;
        union { unsigned short u[4]; uint2 v; } o;
        o.u[0]=f2bf(acc[mt][nt][0]); o.u[1]=f2bf(acc[mt][nt][1]);
        o.u[2]=f2bf(acc[mt][nt][2]); o.u[3]=f2bf(acc[mt][nt][3]);
        *(uint2*)(gx + ((size_t)(dir*16 + (b0 >> 2))*SS + t)*4096 + col*4) = o.v;
      }
  }
}

// ---------------- batch-partitioned bidirectional LSTM, 32 blocks, ONE barrier/step ----------------
// Block: dir = blk>>4, bg = blk&15 -> batch rows bg*4..+3. 512 threads (8 waves).
// Wave w: all 4 gates for cols w*32..+31. fp8 Whh resident in regs.
// Gate exchange is INTRA-WAVE (rows 0-3 live in lanes 0-15): tiny per-wave LDS bounce,
// lgkmcnt-only sync. Combine on all 64 lanes (lane = batch kq x col nl, 2 h each),
// writing the next fp8 A-tile directly (byte-packed) + bf16 h to global.
#define WSC 64.0f
#define HSC 16.0f
#define ISC (1.0f/(WSC*HSC))

__global__ __launch_bounds__(512,1) void k_lstm(
    const unsigned short* __restrict__ gx,
    const float* __restrict__ Whh_f, const float* __restrict__ bih_f, const float* __restrict__ bhh_f,
    const float* __restrict__ Whh_b, const float* __restrict__ bih_b, const float* __restrict__ bhh_b,
    unsigned short* __restrict__ hf, unsigned short* __restrict__ hb)
{
  __shared__ __align__(16) unsigned char h8[2][16][272];   // fp8 A-tile, double-buffered (8.5 KB)
  __shared__ __align__(16) float xch[8][4][2][16][4];      // per-wave gate bounce (16 KB)

  const int tid  = threadIdx.x;
  const int lane = tid & 63;
  const int w    = tid >> 6;           // 0..7
  const int nl   = lane & 15;
  const int kq   = lane >> 4;          // MFMA k-quarter; in combine = batch row rr
  const int dir  = blockIdx.x >> 4;
  const int bg   = blockIdx.x & 15;    // batch group (4 rows)

  const float* Whh = dir ? Whh_b : Whh_f;
  const float* bih = dir ? bih_b : bih_f;
  const float* bhh = dir ? bhh_b : bhh_f;
  unsigned short* hbuf = dir ? hb : hf;
  const unsigned short* gxd = gx + (size_t)(dir*16 + bg)*SS*4096;

  // Whh -> fp8 B-fragments in regs: wB[gate][q][kt]
  long wB[4][2][8];
#pragma unroll
  for (int g = 0; g < 4; ++g)
#pragma unroll
    for (int q = 0; q < 2; ++q)
#pragma unroll
      for (int kt = 0; kt < 8; ++kt){
        int ncol = g*256 + w*32 + q*16 + nl;
        const float* p = Whh + (size_t)ncol*HH + kt*32 + kq*4;
        float4 lo = *(const float4*)p;
        float4 hi = *(const float4*)(p + 16);
        union { unsigned d[2]; long l; } u;
        u.d[0] = cvt4fp8(lo.x*WSC, lo.y*WSC, lo.z*WSC, lo.w*WSC);
        u.d[1] = cvt4fp8(hi.x*WSC, hi.y*WSC, hi.z*WSC, hi.w*WSC);
        wB[g][q][kt] = u.l;
      }

  // combine mapping: batch rr=kq, cols w*32 + q*16 + nl (q=0,1)
  float bias_c[4][2];
#pragma unroll
  for (int g = 0; g < 4; ++g)
#pragma unroll
    for (int q = 0; q < 2; ++q){
      int col = g*256 + w*32 + q*16 + nl;
      bias_c[g][q] = bih[col] + bhh[col];
    }
  // fp8 A-tile byte offsets for this lane's two h columns (row added later)
  const int bp0 = w*32 + (nl >> 2)*8 + (nl & 3);        // q=0
  const int bp1 = bp0 + 4;                               // q=1

  // zero both A-tile buffers (rows 4..15 stay zero forever)
  for (int i = tid; i < 2176; i += 512) ((unsigned*)h8)[i] = 0;
  __syncthreads();

  float c0 = 0.f, c1 = 0.f;   // cell state for (batch kq, col w*32+q*16+nl)

  // gx regs: gxc[g][q] for (gate g, col, batch kq) — each load wave-coalesced (128B)
  unsigned short gxc[4][2], gxn[4][2];
  {
    const int t0 = dir ? (SS-1) : 0;
    const unsigned short* gp = gxd + (size_t)t0*4096;
#pragma unroll
    for (int g = 0; g < 4; ++g)
#pragma unroll
      for (int q = 0; q < 2; ++q)
        gxc[g][q] = gp[(g*256 + w*32 + q*16 + nl)*4 + kq];
  }

  for (int s = 0; s < SS; ++s){
    const int t = dir ? (SS-1-s) : s;

    // prefetch next-step gx early (completes under MFMA)
    {
      int sn = s + 1;
      int tn = (sn < SS) ? (dir ? (SS-1-sn) : sn) : t;
      const unsigned short* gp = gxd + (size_t)tn*4096;
#pragma unroll
      for (int g = 0; g < 4; ++g)
#pragma unroll
        for (int q = 0; q < 2; ++q)
          gxn[g][q] = gp[(g*256 + w*32 + q*16 + nl)*4 + kq];
    }

    // A-fragments: 8 x ds_read_b64, all lanes (rows 4..15 are zeros)
    const unsigned char* tp8 = &h8[s & 1][0][0];
    long af[8];
#pragma unroll
    for (int kt = 0; kt < 8; ++kt)
      af[kt] = *(const long*)(tp8 + nl*272 + kt*32 + kq*8);

    f32x4 acc[4][2];
#pragma unroll
    for (int g = 0; g < 4; ++g)
#pragma unroll
      for (int q = 0; q < 2; ++q) acc[g][q] = (f32x4){0.f,0.f,0.f,0.f};

#pragma unroll
    for (int kt = 0; kt < 8; ++kt)
#pragma unroll
      for (int g = 0; g < 4; ++g)
#pragma unroll
        for (int q = 0; q < 2; ++q)
          acc[g][q] = __builtin_amdgcn_mfma_f32_16x16x32_fp8_fp8(af[kt], wB[g][q][kt], acc[g][q], 0,0,0);

    // intra-wave gate exchange: lanes 0-15 hold batch rows 0-3 in regs 0-3
    if (kq == 0){
#pragma unroll
      for (int g = 0; g < 4; ++g)
#pragma unroll
        for (int q = 0; q < 2; ++q)
          *(f32x4*)&xch[w][g][q][nl][0] = acc[g][q];   // ds_write_b128, conflict-free
    }
    asm volatile("s_waitcnt lgkmcnt(0)" ::: "memory");

    // combine: lane (batch kq, col nl), q = 0,1
    {
      const int wslot = dir ? t : (s + 1);
      unsigned short* hrow = hbuf + (size_t)(wslot*BB + bg*4 + kq)*HH + w*32 + nl;
      unsigned char* arow = &h8[(s + 1) & 1][kq][0];
#pragma unroll
      for (int q = 0; q < 2; ++q){
        float iv = xch[0][0][0][0][0]; // placeholder to keep shape; real reads below
        (void)iv;
        float i_ = xch[w][0][q][nl][kq]*ISC + bf2f(gxc[0][q]) + bias_c[0][q];
        float f_ = xch[w][1][q][nl][kq]*ISC + bf2f(gxc[1][q]) + bias_c[1][q];
        float g_ = xch[w][2][q][nl][kq]*ISC + bf2f(gxc[2][q]) + bias_c[2][q];
        float o_ = xch[w][3][q][nl][kq]*ISC + bf2f(gxc[3][q]) + bias_c[3][q];
        float cold = q ? c1 : c0;
        float cnew = sigm(f_)*cold + sigm(i_)*ftanh(g_);
        if (q) c1 = cnew; else c0 = cnew;
        float h = sigm(o_)*ftanh(cnew);
        hrow[q*16] = f2bf(h);                          // bf16 h to global
        arow[q ? bp1 : bp0] = cvt1fp8(h*HSC);          // fp8 into next A-tile
      }
    }

#pragma unroll
    for (int g = 0; g < 4; ++g)
#pragma unroll
      for (int q = 0; q < 2; ++q) gxc[g][q] = gxn[g][q];

    __syncthreads();   // next A-tile complete; buffers swap
  }
}

// ---------------- FC via MFMA: logits[p][tag] = [hf(t+1);hb(t)] . fcW[tag] + fcb ----------------
__global__ __launch_bounds__(256,1) void k_fc(
    const unsigned short* __restrict__ hf, const unsigned short* __restrict__ hb,
    const float* __restrict__ fcW, const float* __restrict__ fcb,
    float* __restrict__ logits)
{
  __shared__ unsigned short Bs[32][520];
  __shared__ float fcb_s[32];
  const int tid = threadIdx.x;
  for (int i = tid; i < 32*512; i += 256){
    int tg = i >> 9, k = i & 511;
    Bs[tg][k] = f2bf(fcW[tg*512 + k]);
  }
  if (tid < 32) fcb_s[tid] = fcb[tid];
  __syncthreads();

  const int lane = tid & 63, w = tid >> 6;
  const int nl = lane & 15, kq = lane >> 4;
  const int pbase = blockIdx.x * 128;

  f32x4 acc[2][2];
#pragma unroll
  for (int mt = 0; mt < 2; ++mt)
#pragma unroll
    for (int nt = 0; nt < 2; ++nt) acc[mt][nt] = (f32x4){0.f,0.f,0.f,0.f};

#pragma unroll
  for (int kt = 0; kt < 16; ++kt){
    int k0 = kt*32 + kq*4;
    bf16x8 a[2];
#pragma unroll
    for (int mt = 0; mt < 2; ++mt){
      int p = pbase + w*32 + mt*16 + nl;
      int t = p >> 6, b = p & 63;
      const unsigned short* hrp = (kt < 8)
        ? hf + (size_t)((t+1)*BB + b)*HH + k0
        : hb + (size_t)(t*BB + b)*HH + (k0 - 256);
      short4v lo = *(const short4v*)hrp;
      short4v hi = *(const short4v*)(hrp + 16);
      bf16x8 f = {lo[0],lo[1],lo[2],lo[3],hi[0],hi[1],hi[2],hi[3]};
      a[mt] = f;
    }
#pragma unroll
    for (int nt = 0; nt < 2; ++nt){
      const unsigned short* br = &Bs[nt*16 + nl][k0];
      short4v lo = *(const short4v*)br;
      short4v hi = *(const short4v*)(br + 16);
      bf16x8 bv = {lo[0],lo[1],lo[2],lo[3],hi[0],hi[1],hi[2],hi[3]};
      acc[0][nt] = __builtin_amdgcn_mfma_f32_16x16x32_bf16(a[0], bv, acc[0][nt], 0,0,0);
      acc[1][nt] = __builtin_amdgcn_mfma_f32_16x16x32_bf16(a[1], bv, acc[1][nt], 0,0,0);
    }
  }
#pragma unroll
  for (int mt = 0; mt < 2; ++mt)
#pragma unroll
    for (int nt = 0; nt < 2; ++nt)
#pragma unroll
      for (int r = 0; r < 4; ++r){
        int p = pbase + w*32 + mt*16 + kq*4 + r;
        int tg = nt*16 + nl;
        logits[(size_t)p*TT + tg] = acc[mt][nt][r] + fcb_s[tg];
      }
}

// ---------------- merged CRF: blocks 0-15 den, 16-31 vit, 32-47 num ----------------
__global__ void k_crf(const float* __restrict__ logits, const int* __restrict__ mask,
                      const int* __restrict__ labels,
                      const float* __restrict__ start, const float* __restrict__ endt,
                      const float* __restrict__ trans,
                      float* __restrict__ den, float* __restrict__ num,
                      unsigned char* __restrict__ vhist, float* __restrict__ preds)
{
  __shared__ float tr[1024];
  const int tid = threadIdx.x;
  const int role = blockIdx.x >> 4;
  const int bq   = blockIdx.x & 15;
  if (role != 2){
    for (int i = tid; i < 1024; i += 256) tr[i] = trans[i];
    __syncthreads();
  }
  const int lane = tid & 63, w = tid >> 6;
  const int b = bq*4 + w;
  const int grp = lane >> 5, tp = lane & 31;

  if (role == 0){ // denominator
    float score = start[tp] + logits[(size_t)b*TT + tp];
    for (int s = 1; s < SS; ++s){
      float m = -1e30f;
#pragma unroll
      for (int jj = 0; jj < 16; ++jj){
        int j = grp*16 + jj;
        float v = __shfl(score, j) + tr[j*32 + tp];
        m = fmaxf(m, v);
      }
      m = fmaxf(m, __shfl_xor(m, 32));
      float ssum = 0.f;
#pragma unroll
      for (int jj = 0; jj < 16; ++jj){
        int j = grp*16 + jj;
        float v = __shfl(score, j) + tr[j*32 + tp];
        ssum += __expf(v - m);
      }
      ssum += __shfl_xor(ssum, 32);
      float ns = m + __logf(ssum) + logits[(size_t)(s*BB + b)*TT + tp];
      score = mask[b*SS + s] ? ns : score;
    }
    float v = score + endt[tp];
    float mm = v;
    for (int d = 1; d < 32; d <<= 1) mm = fmaxf(mm, __shfl_xor(mm, d));
    float se = __expf(v - mm);
    for (int d = 1; d < 32; d <<= 1) se += __shfl_xor(se, d);
    if (lane == 0) den[b] = mm + __logf(se);
  } else if (role == 1){ // viterbi
    float score = start[tp] + logits[(size_t)b*TT + tp];
    for (int s = 1; s < SS; ++s){
      float m = -1e30f; int am = 0;
#pragma unroll
      for (int jj = 0; jj < 16; ++jj){
        int j = grp*16 + jj;
        float v = __shfl(score, j) + tr[j*32 + tp];
        if (v > m){ m = v; am = j; }
      }
      float om = __shfl_xor(m, 32); int oam = __shfl_xor(am, 32);
      if (om > m || (om == m && oam < am)){ m = om; am = oam; }
      int mk = mask[b*SS + s];
      float ns = m + logits[(size_t)(s*BB + b)*TT + tp];
      int idx = mk ? am : tp;
      if (grp == 0) vhist[(size_t)(s*BB + b)*32 + tp] = (unsigned char)idx;
      score = mk ? ns : score;
    }
    float v = score + endt[tp]; int a = tp;
    for (int d = 1; d < 32; d <<= 1){
      float ov = __shfl_xor(v, d); int oa = __shfl_xor(a, d);
      if (ov > v || (ov == v && oa < a)){ v = ov; a = oa; }
    }
    int tag = __shfl(a, 0);
    if (lane == 0) preds[(size_t)b*SS + SS - 1] = (float)tag;
    for (int s = SS - 1; s >= 1; --s){
      int rv = vhist[(size_t)(s*BB + b)*32 + tp];
      int pv = __shfl(rv, tag);
      if (lane == 0) preds[(size_t)b*SS + s - 1] = (float)pv;
      tag = pv;
    }
  } else { // numerator
    float acc = 0.f; int mcnt = 0;
    for (int s = lane; s < SS; s += 64){
      int mk = mask[b*SS + s];
      mcnt += mk;
      if (s >= 1){
        int tg = labels[b*SS + s], tpp = labels[b*SS + s - 1];
        float v = trans[tpp*32 + tg] + logits[(size_t)(s*BB + b)*TT + tg];
        acc += mk ? v : 0.f;
      }
    }
    for (int d = 1; d < 64; d <<= 1){ acc += __shfl_xor(acc, d); mcnt += __shfl_xor(mcnt, d); }
    if (lane == 0){
      int t0 = labels[b*SS];
      int tl = labels[b*SS + (mcnt - 1)];
      num[b] = start[t0] + logits[(size_t)b*TT + t0] + acc + endt[tl];
    }
  }
}

// ---------------- loss ----------------
__global__ void k_loss(const float* __restrict__ num, const float* __restrict__ den,
                       float* __restrict__ out)
{
  int l = threadIdx.x;
  float v = num[l] - den[l];
  for (int d = 1; d < 64; d <<= 1) v += __shfl_xor(v, d);
  if (l == 0) out[BB*SS] = -v;
}

extern "C" void kernel_launch(void* const* d_in, const int* in_sizes, int n_in,
                              void* d_out, int out_size, void* d_ws, size_t ws_size,
                              hipStream_t stream)
{
  const int*   seq       = (const int*)  d_in[0];
  const int*   mask      = (const int*)  d_in[1];
  const int*   labels    = (const int*)  d_in[2];
  const float* embedding = (const float*)d_in[3];
  const float* Wih_f     = (const float*)d_in[4];
  const float* Whh_f     = (const float*)d_in[5];
  const float* bih_f     = (const float*)d_in[6];
  const float* bhh_f     = (const float*)d_in[7];
  const float* Wih_b     = (const float*)d_in[8];
  const float* Whh_b     = (const float*)d_in[9];
  const float* bih_b     = (const float*)d_in[10];
  const float* bhh_b     = (const float*)d_in[11];
  const float* fcW       = (const float*)d_in[12];
  const float* fcb       = (const float*)d_in[13];
  const float* start_t   = (const float*)d_in[14];
  const float* end_t     = (const float*)d_in[15];
  const float* trans     = (const float*)d_in[16];

  char* ws = (char*)d_ws;
  size_t off = 0;
  unsigned short* gxb = (unsigned short*)(ws + off); off += (size_t)2*SS*1024*64*2;     // 128 MiB
  unsigned short* hf  = (unsigned short*)(ws + off); off += (size_t)(SS+1)*BB*HH*2;     // 16 MiB
  unsigned short* hb  = (unsigned short*)(ws + off); off += (size_t)(SS+1)*BB*HH*2;     // 16 MiB
  float*          lgt = (float*)(ws + off);          off += (size_t)SS*BB*TT*4;         // 4 MiB
  unsigned char*  vh  = (unsigned char*)(ws + off);  off += (size_t)SS*BB*TT;           // 1 MiB
  float*          den = (float*)(ws + off);          off += 256;
  float*          num = (float*)(ws + off);          off += 256;

  k_xgemm<<<dim3(256,2), 256, 0, stream>>>(seq, embedding, Wih_f, Wih_b, gxb);
  k_lstm<<<32, 512, 0, stream>>>(gxb, Whh_f, bih_f, bhh_f, Whh_b, bih_b, bhh_b, hf, hb);
  k_fc<<<256, 256, 0, stream>>>(hf, hb, fcW, fcb, lgt);
  k_crf<<<48, 256, 0, stream>>>(lgt, mask, labels, start_t, end_t, trans, den, num, vh, (float*)d_out);
  k_loss<<<1, 64, 0, stream>>>(num, den, (float*)d_out);
}

// Round 10
// 1529.860 us; speedup vs baseline: 2.1310x; 1.1367x over previous
//
#include <hip/hip_runtime.h>
#include <stdint.h>

#define SS 512
#define BB 64
#define HH 256
#define TT 32

typedef __attribute__((ext_vector_type(8))) short bf16x8;
typedef __attribute__((ext_vector_type(4))) short short4v;
typedef __attribute__((ext_vector_type(4))) float f32x4;

__device__ __forceinline__ unsigned short f2bf(float f){
  unsigned u = __float_as_uint(f);
  unsigned r = (u + 0x7FFFu + ((u >> 16) & 1u)) >> 16;
  return (unsigned short)r;
}
__device__ __forceinline__ float bf2f(unsigned short s){
  return __uint_as_float(((unsigned)s) << 16);
}
__device__ __forceinline__ float sigm(float x){ return 1.0f/(1.0f+__expf(-x)); }
__device__ __forceinline__ float ftanh(float x){
  float e = __expf(2.f*x);
  return 1.f - 2.f/(e + 1.f);
}
__device__ __forceinline__ unsigned cvt4fp8(float a0, float a1, float a2, float a3){
  int d = __builtin_amdgcn_cvt_pk_fp8_f32(a0, a1, 0, false);
  d = __builtin_amdgcn_cvt_pk_fp8_f32(a2, a3, d, true);
  return (unsigned)d;
}
__device__ __forceinline__ unsigned char cvt1fp8(float a){
  int d = __builtin_amdgcn_cvt_pk_fp8_f32(a, a, 0, false);
  return (unsigned char)(d & 0xFF);
}

// swizzled-LDS fragment read (used by k_xgemm only)
__device__ __forceinline__ bf16x8 afrag(const unsigned short* A, int mt, int ktp, int nl, int kq){
  int m = mt*16 + nl;
  int sw = (m & 7) << 3;
  int kk = ktp*32 + kq*4;
  short4v lo = *(const short4v*)(A + (m << 8) + (kk ^ sw));
  short4v hi = *(const short4v*)(A + (m << 8) + ((kk + 16) ^ sw));
  bf16x8 r = {lo[0],lo[1],lo[2],lo[3],hi[0],hi[1],hi[2],hi[3]};
  return r;
}

// ---------------- fused gather + x@Wih^T GEMM -> gx bf16 [dir*16+bg][t][col(1024)][b(4)] ----------------
__global__ __launch_bounds__(256,1) void k_xgemm(
    const int* __restrict__ seq, const float* __restrict__ emb,
    const float* __restrict__ Wih_f, const float* __restrict__ Wih_b,
    unsigned short* __restrict__ gx)
{
  __shared__ __align__(16) unsigned short A_l[128*256];  // 64 KiB
  __shared__ __align__(16) unsigned short B_l[64*256];   // 32 KiB

  const int tid = threadIdx.x;
  const int lane = tid & 63, w = tid >> 6;
  const int nl = lane & 15, kq = lane >> 4;
  const int pbase = blockIdx.x * 128;
  const int dir = blockIdx.y;
  const float* Wih = dir ? Wih_b : Wih_f;

#pragma unroll
  for (int i = 0; i < 16; ++i){
    int c = tid + i*256;
    int m = c >> 5, k8 = c & 31;
    int p = pbase + m, t = p >> 6, b = p & 63;
    int er = seq[b*SS + t];
    const float* s = emb + (size_t)er*HH + k8*8;
    float4 x0 = *(const float4*)s, x1 = *(const float4*)(s+4);
    union { unsigned short u[8]; uint4 v; } o;
    o.u[0]=f2bf(x0.x); o.u[1]=f2bf(x0.y); o.u[2]=f2bf(x0.z); o.u[3]=f2bf(x0.w);
    o.u[4]=f2bf(x1.x); o.u[5]=f2bf(x1.y); o.u[6]=f2bf(x1.z); o.u[7]=f2bf(x1.w);
    *(uint4*)&A_l[(m << 8) + ((k8*8) ^ ((m & 7) << 3))] = o.v;
  }

  for (int nb = 0; nb < 16; ++nb){
    __syncthreads();
#pragma unroll
    for (int i = 0; i < 8; ++i){
      int c = tid + i*256;
      int m = c >> 5, k8 = c & 31;
      const float* s = Wih + (size_t)(nb*64 + m)*HH + k8*8;
      float4 x0 = *(const float4*)s, x1 = *(const float4*)(s+4);
      union { unsigned short u[8]; uint4 v; } o;
      o.u[0]=f2bf(x0.x); o.u[1]=f2bf(x0.y); o.u[2]=f2bf(x0.z); o.u[3]=f2bf(x0.w);
      o.u[4]=f2bf(x1.x); o.u[5]=f2bf(x1.y); o.u[6]=f2bf(x1.z); o.u[7]=f2bf(x1.w);
      *(uint4*)&B_l[(m << 8) + ((k8*8) ^ ((m & 7) << 3))] = o.v;
    }
    __syncthreads();

    f32x4 acc[2][4];
#pragma unroll
    for (int mt = 0; mt < 2; ++mt)
#pragma unroll
      for (int nt = 0; nt < 4; ++nt) acc[mt][nt] = (f32x4){0.f,0.f,0.f,0.f};

#pragma unroll
    for (int kt = 0; kt < 8; ++kt){
      bf16x8 a0 = afrag(A_l, w*2+0, kt, nl, kq);
      bf16x8 a1 = afrag(A_l, w*2+1, kt, nl, kq);
#pragma unroll
      for (int nt = 0; nt < 4; ++nt){
        bf16x8 bv = afrag(B_l, nt, kt, nl, kq);
        acc[0][nt] = __builtin_amdgcn_mfma_f32_16x16x32_bf16(a0, bv, acc[0][nt], 0,0,0);
        acc[1][nt] = __builtin_amdgcn_mfma_f32_16x16x32_bf16(a1, bv, acc[1][nt], 0,0,0);
      }
    }

#pragma unroll
    for (int mt = 0; mt < 2; ++mt)
#pragma unroll
      for (int nt = 0; nt < 4; ++nt){
        int p0 = pbase + w*32 + mt*16 + kq*4;
        int t = p0 >> 6, b0 = p0 & 63;
        int col = nb*64 + nt*16 + nl;
        union { unsigned short u[4]; uint2 v; } o;
        o.u[0]=f2bf(acc[mt][nt][0]); o.u[1]=f2bf(acc[mt][nt][1]);
        o.u[2]=f2bf(acc[mt][nt][2]); o.u[3]=f2bf(acc[mt][nt][3]);
        *(uint2*)(gx + ((size_t)(dir*16 + (b0 >> 2))*SS + t)*4096 + col*4) = o.v;
      }
  }
}

// ---------------- batch-partitioned bidirectional LSTM, 32 blocks, lgkm-only barrier ----------------
#define WSC 64.0f
#define HSC 16.0f
#define ISC (1.0f/(WSC*HSC))

__global__ __launch_bounds__(512,1) void k_lstm(
    const unsigned short* __restrict__ gx,
    const float* __restrict__ Whh_f, const float* __restrict__ bih_f, const float* __restrict__ bhh_f,
    const float* __restrict__ Whh_b, const float* __restrict__ bih_b, const float* __restrict__ bhh_b,
    unsigned short* __restrict__ hf, unsigned short* __restrict__ hb)
{
  __shared__ __align__(16) unsigned char h8[2][16][272];   // fp8 A-tile, double-buffered
  __shared__ __align__(16) float xch[8][4][2][16][4];      // per-wave gate bounce

  const int tid  = threadIdx.x;
  const int lane = tid & 63;
  const int w    = tid >> 6;           // 0..7
  const int nl   = lane & 15;
  const int kq   = lane >> 4;
  const int dir  = blockIdx.x >> 4;
  const int bg   = blockIdx.x & 15;

  const float* Whh = dir ? Whh_b : Whh_f;
  const float* bih = dir ? bih_b : bih_f;
  const float* bhh = dir ? bhh_b : bhh_f;
  unsigned short* hbuf = dir ? hb : hf;
  const unsigned short* gxd = gx + (size_t)(dir*16 + bg)*SS*4096;

  // Whh -> fp8 B-fragments in regs
  long wB[4][2][8];
#pragma unroll
  for (int g = 0; g < 4; ++g)
#pragma unroll
    for (int q = 0; q < 2; ++q)
#pragma unroll
      for (int kt = 0; kt < 8; ++kt){
        int ncol = g*256 + w*32 + q*16 + nl;
        const float* p = Whh + (size_t)ncol*HH + kt*32 + kq*4;
        float4 lo = *(const float4*)p;
        float4 hi = *(const float4*)(p + 16);
        union { unsigned d[2]; long l; } u;
        u.d[0] = cvt4fp8(lo.x*WSC, lo.y*WSC, lo.z*WSC, lo.w*WSC);
        u.d[1] = cvt4fp8(hi.x*WSC, hi.y*WSC, hi.z*WSC, hi.w*WSC);
        wB[g][q][kt] = u.l;
      }

  float bias_c[4][2];
#pragma unroll
  for (int g = 0; g < 4; ++g)
#pragma unroll
    for (int q = 0; q < 2; ++q){
      int col = g*256 + w*32 + q*16 + nl;
      bias_c[g][q] = bih[col] + bhh[col];
    }
  const int bp0 = w*32 + (nl >> 2)*8 + (nl & 3);
  const int bp1 = bp0 + 4;

  for (int i = tid; i < 2176; i += 512) ((unsigned*)h8)[i] = 0;
  __syncthreads();

  float c0 = 0.f, c1 = 0.f;

  unsigned short gxc[4][2], gxn[4][2];
  {
    const int t0 = dir ? (SS-1) : 0;
    const unsigned short* gp = gxd + (size_t)t0*4096;
#pragma unroll
    for (int g = 0; g < 4; ++g)
#pragma unroll
      for (int q = 0; q < 2; ++q)
        gxc[g][q] = gp[(g*256 + w*32 + q*16 + nl)*4 + kq];
  }

  for (int s = 0; s < SS; ++s){
    const int t = dir ? (SS-1-s) : s;

    // prefetch next-step gx (retires under MFMA; never drained in-loop)
    {
      int sn = s + 1;
      int tn = (sn < SS) ? (dir ? (SS-1-sn) : sn) : t;
      const unsigned short* gp = gxd + (size_t)tn*4096;
#pragma unroll
      for (int g = 0; g < 4; ++g)
#pragma unroll
        for (int q = 0; q < 2; ++q)
          gxn[g][q] = gp[(g*256 + w*32 + q*16 + nl)*4 + kq];
    }

    // A-fragments: 8 x ds_read_b64 (rows 4..15 are constant zeros)
    const unsigned char* tp8 = &h8[s & 1][0][0];
    long af[8];
#pragma unroll
    for (int kt = 0; kt < 8; ++kt)
      af[kt] = *(const long*)(tp8 + nl*272 + kt*32 + kq*8);

    f32x4 acc[4][2];
#pragma unroll
    for (int g = 0; g < 4; ++g)
#pragma unroll
      for (int q = 0; q < 2; ++q) acc[g][q] = (f32x4){0.f,0.f,0.f,0.f};

#pragma unroll
    for (int kt = 0; kt < 8; ++kt)
#pragma unroll
      for (int g = 0; g < 4; ++g)
#pragma unroll
        for (int q = 0; q < 2; ++q)
          acc[g][q] = __builtin_amdgcn_mfma_f32_16x16x32_fp8_fp8(af[kt], wB[g][q][kt], acc[g][q], 0,0,0);

    // intra-wave gate exchange
    if (kq == 0){
#pragma unroll
      for (int g = 0; g < 4; ++g)
#pragma unroll
        for (int q = 0; q < 2; ++q)
          *(f32x4*)&xch[w][g][q][nl][0] = acc[g][q];
    }
    asm volatile("s_waitcnt lgkmcnt(0)" ::: "memory");

    // combine: lane (batch kq, col nl), q = 0,1
    {
      const int wslot = dir ? t : (s + 1);
      unsigned short* hrow = hbuf + (size_t)(wslot*BB + bg*4 + kq)*HH + w*32 + nl;
      unsigned char* arow = &h8[(s + 1) & 1][kq][0];
#pragma unroll
      for (int q = 0; q < 2; ++q){
        float i_ = xch[w][0][q][nl][kq]*ISC + bf2f(gxc[0][q]) + bias_c[0][q];
        float f_ = xch[w][1][q][nl][kq]*ISC + bf2f(gxc[1][q]) + bias_c[1][q];
        float g_ = xch[w][2][q][nl][kq]*ISC + bf2f(gxc[2][q]) + bias_c[2][q];
        float o_ = xch[w][3][q][nl][kq]*ISC + bf2f(gxc[3][q]) + bias_c[3][q];
        float cold = q ? c1 : c0;
        float cnew = sigm(f_)*cold + sigm(i_)*ftanh(g_);
        if (q) c1 = cnew; else c0 = cnew;
        float h = sigm(o_)*ftanh(cnew);
        hrow[q*16] = f2bf(h);                          // global store — not drained in-loop
        arow[q ? bp1 : bp0] = cvt1fp8(h*HSC);          // fp8 into next A-tile (LDS)
      }
    }

#pragma unroll
    for (int g = 0; g < 4; ++g)
#pragma unroll
      for (int q = 0; q < 2; ++q) gxc[g][q] = gxn[g][q];

    // lgkm-only barrier: LDS (h8) is the only cross-wave dependency.
    asm volatile("s_waitcnt lgkmcnt(0)" ::: "memory");
    __builtin_amdgcn_s_barrier();
    asm volatile("" ::: "memory");
  }
}

// ---------------- FC via MFMA, LDS-staged A (coalesced h reads) ----------------
__global__ __launch_bounds__(256,1) void k_fc(
    const unsigned short* __restrict__ hf, const unsigned short* __restrict__ hb,
    const float* __restrict__ fcW, const float* __restrict__ fcb,
    float* __restrict__ logits)
{
  __shared__ unsigned short Bs[32][516];     // fcW bf16 [tag][k]
  __shared__ unsigned short Ah[4][32][260];  // per-wave h half-tile [row][k-local]
  __shared__ float fcb_s[32];
  const int tid = threadIdx.x;
  for (int i = tid; i < 32*512; i += 256){
    int tg = i >> 9, k = i & 511;
    Bs[tg][k] = f2bf(fcW[tg*512 + k]);
  }
  if (tid < 32) fcb_s[tid] = fcb[tid];
  __syncthreads();

  const int lane = tid & 63, w = tid >> 6;
  const int nl = lane & 15, kq = lane >> 4;
  const int pbase = blockIdx.x * 128;

  f32x4 acc[2][2];
#pragma unroll
  for (int mt = 0; mt < 2; ++mt)
#pragma unroll
    for (int nt = 0; nt < 2; ++nt) acc[mt][nt] = (f32x4){0.f,0.f,0.f,0.f};

  for (int half = 0; half < 2; ++half){
    // stage this wave's 32 rows (512B each, fully coalesced)
    for (int rr = 0; rr < 32; ++rr){
      int p = pbase + w*32 + rr;
      int t = p >> 6, b = p & 63;
      const unsigned short* src = half ? (hb + (size_t)(t*BB + b)*HH)
                                       : (hf + (size_t)((t+1)*BB + b)*HH);
      *(uint2*)&Ah[w][rr][lane*4] = *(const uint2*)(src + lane*4);
    }
    // wave-private tile: compiler inserts lgkmcnt for the ds deps
#pragma unroll
    for (int kt = 0; kt < 8; ++kt){
      int kl = kt*32 + kq*4;       // k-local within half
      bf16x8 a[2];
#pragma unroll
      for (int mt = 0; mt < 2; ++mt){
        const unsigned short* ar = &Ah[w][mt*16 + nl][kl];
        short4v lo = *(const short4v*)ar;
        short4v hi = *(const short4v*)(ar + 16);
        bf16x8 f = {lo[0],lo[1],lo[2],lo[3],hi[0],hi[1],hi[2],hi[3]};
        a[mt] = f;
      }
#pragma unroll
      for (int nt = 0; nt < 2; ++nt){
        const unsigned short* br = &Bs[nt*16 + nl][half*256 + kl];
        short4v lo = *(const short4v*)br;
        short4v hi = *(const short4v*)(br + 16);
        bf16x8 bv = {lo[0],lo[1],lo[2],lo[3],hi[0],hi[1],hi[2],hi[3]};
        acc[0][nt] = __builtin_amdgcn_mfma_f32_16x16x32_bf16(a[0], bv, acc[0][nt], 0,0,0);
        acc[1][nt] = __builtin_amdgcn_mfma_f32_16x16x32_bf16(a[1], bv, acc[1][nt], 0,0,0);
      }
    }
  }
#pragma unroll
  for (int mt = 0; mt < 2; ++mt)
#pragma unroll
    for (int nt = 0; nt < 2; ++nt)
#pragma unroll
      for (int r = 0; r < 4; ++r){
        int p = pbase + w*32 + mt*16 + kq*4 + r;
        int tg = nt*16 + nl;
        logits[(size_t)p*TT + tg] = acc[mt][nt][r] + fcb_s[tg];
      }
}

// ---------------- merged CRF: blocks 0-15 den, 16-31 vit (LDS hist), 32-47 num ----------------
__global__ void k_crf(const float* __restrict__ logits, const int* __restrict__ mask,
                      const int* __restrict__ labels,
                      const float* __restrict__ start, const float* __restrict__ endt,
                      const float* __restrict__ trans,
                      float* __restrict__ den, float* __restrict__ num,
                      float* __restrict__ preds)
{
  __shared__ float tr[1024];
  __shared__ unsigned char vh_l[4][SS-1][32];   // viterbi history, per-wave batch
  const int tid = threadIdx.x;
  const int role = blockIdx.x >> 4;
  const int bq   = blockIdx.x & 15;
  if (role != 2){
    for (int i = tid; i < 1024; i += 256) tr[i] = trans[i];
    __syncthreads();
  }
  const int lane = tid & 63, w = tid >> 6;
  const int b = bq*4 + w;
  const int grp = lane >> 5, tp = lane & 31;

  if (role == 0){ // denominator
    float score = start[tp] + logits[(size_t)b*TT + tp];
    float em_c = logits[(size_t)(BB + b)*TT + tp];
    int   mk_c = mask[b*SS + 1];
    for (int s = 1; s < SS; ++s){
      int sn = (s + 1 < SS) ? s + 1 : s;
      float em_n = logits[(size_t)(sn*BB + b)*TT + tp];
      int   mk_n = mask[b*SS + sn];
      float m = -1e30f;
#pragma unroll
      for (int jj = 0; jj < 16; ++jj){
        int j = grp*16 + jj;
        float v = __shfl(score, j) + tr[j*32 + tp];
        m = fmaxf(m, v);
      }
      m = fmaxf(m, __shfl_xor(m, 32));
      float ssum = 0.f;
#pragma unroll
      for (int jj = 0; jj < 16; ++jj){
        int j = grp*16 + jj;
        float v = __shfl(score, j) + tr[j*32 + tp];
        ssum += __expf(v - m);
      }
      ssum += __shfl_xor(ssum, 32);
      float ns = m + __logf(ssum) + em_c;
      score = mk_c ? ns : score;
      em_c = em_n; mk_c = mk_n;
    }
    float v = score + endt[tp];
    float mm = v;
    for (int d = 1; d < 32; d <<= 1) mm = fmaxf(mm, __shfl_xor(mm, d));
    float se = __expf(v - mm);
    for (int d = 1; d < 32; d <<= 1) se += __shfl_xor(se, d);
    if (lane == 0) den[b] = mm + __logf(se);
  } else if (role == 1){ // viterbi, history in LDS
    float score = start[tp] + logits[(size_t)b*TT + tp];
    float em_c = logits[(size_t)(BB + b)*TT + tp];
    int   mk_c = mask[b*SS + 1];
    for (int s = 1; s < SS; ++s){
      int sn = (s + 1 < SS) ? s + 1 : s;
      float em_n = logits[(size_t)(sn*BB + b)*TT + tp];
      int   mk_n = mask[b*SS + sn];
      float m = -1e30f; int am = 0;
#pragma unroll
      for (int jj = 0; jj < 16; ++jj){
        int j = grp*16 + jj;
        float v = __shfl(score, j) + tr[j*32 + tp];
        if (v > m){ m = v; am = j; }
      }
      float om = __shfl_xor(m, 32); int oam = __shfl_xor(am, 32);
      if (om > m || (om == m && oam < am)){ m = om; am = oam; }
      float ns = m + em_c;
      int idx = mk_c ? am : tp;
      if (grp == 0) vh_l[w][s-1][tp] = (unsigned char)idx;
      score = mk_c ? ns : score;
      em_c = em_n; mk_c = mk_n;
    }
    float v = score + endt[tp]; int a = tp;
    for (int d = 1; d < 32; d <<= 1){
      float ov = __shfl_xor(v, d); int oa = __shfl_xor(a, d);
      if (ov > v || (ov == v && oa < a)){ v = ov; a = oa; }
    }
    int tag = __shfl(a, 0);
    if (lane == 0) preds[(size_t)b*SS + SS - 1] = (float)tag;
    for (int s = SS - 1; s >= 1; --s){
      int rv = vh_l[w][s-1][tp];
      int pv = __shfl(rv, tag);
      if (lane == 0) preds[(size_t)b*SS + s - 1] = (float)pv;
      tag = pv;
    }
  } else { // numerator
    float acc = 0.f; int mcnt = 0;
    for (int s = lane; s < SS; s += 64){
      int mk = mask[b*SS + s];
      mcnt += mk;
      if (s >= 1){
        int tg = labels[b*SS + s], tpp = labels[b*SS + s - 1];
        float v = trans[tpp*32 + tg] + logits[(size_t)(s*BB + b)*TT + tg];
        acc += mk ? v : 0.f;
      }
    }
    for (int d = 1; d < 64; d <<= 1){ acc += __shfl_xor(acc, d); mcnt += __shfl_xor(mcnt, d); }
    if (lane == 0){
      int t0 = labels[b*SS];
      int tl = labels[b*SS + (mcnt - 1)];
      num[b] = start[t0] + logits[(size_t)b*TT + t0] + acc + endt[tl];
    }
  }
}

// ---------------- loss ----------------
__global__ void k_loss(const float* __restrict__ num, const float* __restrict__ den,
                       float* __restrict__ out)
{
  int l = threadIdx.x;
  float v = num[l] - den[l];
  for (int d = 1; d < 64; d <<= 1) v += __shfl_xor(v, d);
  if (l == 0) out[BB*SS] = -v;
}

extern "C" void kernel_launch(void* const* d_in, const int* in_sizes, int n_in,
                              void* d_out, int out_size, void* d_ws, size_t ws_size,
                              hipStream_t stream)
{
  const int*   seq       = (const int*)  d_in[0];
  const int*   mask      = (const int*)  d_in[1];
  const int*   labels    = (const int*)  d_in[2];
  const float* embedding = (const float*)d_in[3];
  const float* Wih_f     = (const float*)d_in[4];
  const float* Whh_f     = (const float*)d_in[5];
  const float* bih_f     = (const float*)d_in[6];
  const float* bhh_f     = (const float*)d_in[7];
  const float* Wih_b     = (const float*)d_in[8];
  const float* Whh_b     = (const float*)d_in[9];
  const float* bih_b     = (const float*)d_in[10];
  const float* bhh_b     = (const float*)d_in[11];
  const float* fcW       = (const float*)d_in[12];
  const float* fcb       = (const float*)d_in[13];
  const float* start_t   = (const float*)d_in[14];
  const float* end_t     = (const float*)d_in[15];
  const float* trans     = (const float*)d_in[16];

  char* ws = (char*)d_ws;
  size_t off = 0;
  unsigned short* gxb = (unsigned short*)(ws + off); off += (size_t)2*SS*1024*64*2;     // 128 MiB
  unsigned short* hf  = (unsigned short*)(ws + off); off += (size_t)(SS+1)*BB*HH*2;     // 16 MiB
  unsigned short* hb  = (unsigned short*)(ws + off); off += (size_t)(SS+1)*BB*HH*2;     // 16 MiB
  float*          lgt = (float*)(ws + off);          off += (size_t)SS*BB*TT*4;         // 4 MiB
  float*          den = (float*)(ws + off);          off += 256;
  float*          num = (float*)(ws + off);          off += 256;

  k_xgemm<<<dim3(256,2), 256, 0, stream>>>(seq, embedding, Wih_f, Wih_b, gxb);
  k_lstm<<<32, 512, 0, stream>>>(gxb, Whh_f, bih_f, bhh_f, Whh_b, bih_b, bhh_b, hf, hb);
  k_fc<<<256, 256, 0, stream>>>(hf, hb, fcW, fcb, lgt);
  k_crf<<<48, 256, 0, stream>>>(lgt, mask, labels, start_t, end_t, trans, den, num, (float*)d_out);
  k_loss<<<1, 64, 0, stream>>>(num, den, (float*)d_out);
}